// Round 4
// baseline (3981.483 us; speedup 1.0000x reference)
//
#include <hip/hip_runtime.h>
#include <math.h>

// Forbid fma contraction for every expression in this file (np-matching arithmetic).
#pragma clang fp contract(off)

#define NB 8
#define NP 8192
#define NS 2048
#define NK 32

// Decision-critical f32 ops as raw VALU instructions — cannot be contracted.
// (Used by ball_kernel; fps relies on the file-wide contract(off).)
__device__ __forceinline__ float fsub(float a, float b) {
  float r; asm("v_sub_f32 %0, %1, %2" : "=v"(r) : "v"(a), "v"(b)); return r;
}
__device__ __forceinline__ float fmul(float a, float b) {
  float r; asm("v_mul_f32 %0, %1, %2" : "=v"(r) : "v"(a), "v"(b)); return r;
}
__device__ __forceinline__ float fadd(float a, float b) {
  float r; asm("v_add_f32 %0, %1, %2" : "=v"(r) : "v"(a), "v"(b)); return r;
}

// ---------------- FPS: LDS-resident points (SoA planes), 512 threads x 16 pts ----------------
// Rounds 0-3 post-mortem: the compiler refuses to keep the 48-float coordinate
// set VGPR-resident (VGPR_Count 32-52 regardless of pins; volatile asm fixes
// execution, not liveness — spill/reload inside the loop is always legal), so
// every iteration re-fetched 96 KB/CU from L2 (~1750 cyc, the dominant term;
// VALU floor is 768 cyc). Fix: stage all points in LDS SoA planes (96 KiB,
// fits 160 KiB/CU at our 1 block/CU). ds_read_b128 at lane-stride 16 B is
// conflict-free; LDS floor = 96 KiB / 128 B/cyc = 768 cyc/iter, overlapping
// VALU across the 8 waves. The compiler cannot reintroduce L2 traffic.
//
// Exact semantics preserved: unfused f32 distances ((dx*dx+dy*dy)+dz*dz under
// contract(off)); u64 (key<<32 | ~idx) max == (max key, lowest index) ==
// np.argmax first-occurrence. Thread t owns points j*2048 + 4t + k; ascending
// local id (j,k) => ascending global idx, strict '>' keeps the lowest.
__global__ __launch_bounds__(512, 2) void fps_kernel(const float* __restrict__ xyz,
                                                     float* __restrict__ new_xyz) {
  __shared__ __align__(16) float splanes[3 * NP];   // 96 KiB: sx, sy, sz
  __shared__ unsigned long long wbest[2][8];
  float* sx = splanes;
  float* sy = splanes + NP;
  float* sz = splanes + 2 * NP;

  const int b = blockIdx.x;
  const int tid = threadIdx.x;
  const int lane = tid & 63, wv = tid >> 6;
  const float* xb = xyz + (size_t)b * NP * 3;

  // ---- stage global AoS -> LDS SoA (one-time; ~0.1% of kernel) ----
  for (int i = 0; i < 16; i++) {
    int p = tid * 16 + i;
    sx[p] = xb[p * 3 + 0];
    sy[p] = xb[p * 3 + 1];
    sz[p] = xb[p * 3 + 2];
  }
  __syncthreads();

  float dist[16];
#pragma unroll
  for (int i = 0; i < 16; i++) dist[i] = 1e10f;

  float fx = sx[0], fy = sy[0], fz = sz[0];   // farthest = index 0 at t=0
  for (int t = 0; t < NS; t++) {
    if (tid == 0) {
      float* o = new_xyz + ((size_t)b * NS + t) * 3;
      o[0] = fx; o[1] = fy; o[2] = fz;
    }
    const int par = t & 1;
    float lmax = -1.0f; int li = 0;
#define FPS_STEP(lid, xs, ys, zs) { \
      float dx = (xs) - fx; \
      float dy = (ys) - fy; \
      float dz = (zs) - fz; \
      float d = dx * dx + dy * dy + dz * dz;  /* contract(off): 3 mul + 2 add */ \
      float nd = fminf(dist[lid], d); \
      dist[lid] = nd; \
      bool gt = nd > lmax; \
      li = gt ? (lid) : li; \
      lmax = gt ? nd : lmax; }
#pragma unroll
    for (int j = 0; j < 4; j++) {
      const int base = j * 2048 + (tid << 2);
      float4 xv = *(const float4*)&sx[base];
      float4 yv = *(const float4*)&sy[base];
      float4 zv = *(const float4*)&sz[base];
      FPS_STEP(j * 4 + 0, xv.x, yv.x, zv.x)
      FPS_STEP(j * 4 + 1, xv.y, yv.y, zv.y)
      FPS_STEP(j * 4 + 2, xv.z, yv.z, zv.z)
      FPS_STEP(j * 4 + 3, xv.w, yv.w, zv.w)
    }
#undef FPS_STEP
    // global idx of this thread's best: p = (li>>2)*2048 + 4*tid + (li&3)
    unsigned idx = (unsigned)(((li >> 2) << 11) | (tid << 2) | (li & 3));
    // dist >= 0 => key bits unsigned-monotone; ~idx -> lowest idx wins ties
    unsigned long long m = ((unsigned long long)__float_as_uint(lmax) << 32)
                         | (unsigned long long)(unsigned)(~idx);
#pragma unroll
    for (int off = 32; off > 0; off >>= 1) {
      unsigned long long o2 = __shfl_down(m, off);
      if (o2 > m) m = o2;
    }
    if (lane == 0) wbest[par][wv] = m;
    __syncthreads();                    // single barrier per iteration
    unsigned long long mm = wbest[par][0];
#pragma unroll
    for (int w = 1; w < 8; w++) { unsigned long long c = wbest[par][w]; if (c > mm) mm = c; }
    int bp = (int)(~(unsigned)(mm & 0xFFFFFFFFull));   // global winner index
    // winner coords from LDS (broadcast read, same bits as staged globals)
    fx = sx[bp]; fy = sy[bp]; fz = sz[bp];
    // parity double-buffer: next iteration writes wbest[1-par] — no WAR race
  }
}

// ---------------- Ball query (unchanged semantics) ----------------
// Writes qsel[cs*32..] to global workspace for the MLP kernel.
__global__ __launch_bounds__(256, 4) void ball_kernel(
    const float* __restrict__ xyz, const float* __restrict__ new_xyz,
    int* __restrict__ qsel_ws) {
  __shared__ __align__(16) float smem[9552];
  float* sd         = smem;                      // 8192 keys
  int* hist4        = (int*)(smem + 8192);       // 4 waves x 256 buckets
  int* cnts         = (int*)(smem + 9216);       // 2
  unsigned* sprefix = (unsigned*)(smem + 9218);
  int* sbelow       = (int*)(smem + 9219);
  int* snear_s      = (int*)(smem + 9220);
  int* wsum         = (int*)(smem + 9224);       // 4
  int* selA         = (int*)(smem + 9232);       // 32
  int* tib          = (int*)(smem + 9264);       // 256

  const int cs = blockIdx.x;
  const int b = cs >> 11;
  const int tid = threadIdx.x;
  const int lane = tid & 63, wv = tid >> 6;
  int* myhist = hist4 + wv * 256;
  const float* xb = xyz + (size_t)b * NP * 3;
  const float cx = new_xyz[cs * 3 + 0], cy = new_xyz[cs * 3 + 1], cz = new_xyz[cs * 3 + 2];
  const float Sc = fadd(fadd(fmul(cx, cx), fmul(cy, cy)), fmul(cz, cz));
  for (int i = lane; i < 256; i += 64) myhist[i] = 0;
  for (int j = 0; j < 32; j++) {
    int p = j * 256 + tid;
    float x = xb[p * 3 + 0], y = xb[p * 3 + 1], z = xb[p * 3 + 2];
    float Sn    = fadd(fadd(fmul(x, x), fmul(y, y)), fmul(z, z));
    float inner = fmaf(cz, z, fmaf(cy, y, fmul(cx, x)));
    float d2    = fsub(fadd(Sc, Sn), fmul(2.0f, inner));
    float kk = __fsqrt_rn(fmaxf(d2, 0.0f));
    sd[p] = kk;
    atomicAdd(&myhist[__float_as_uint(kk) >> 24], 1);
  }
  unsigned prefix = 0; int below = 0;
  for (int round = 0; round < 4; round++) {
    const int shift = 24 - 8 * round;
    if (round > 0) {
      for (int i = lane; i < 256; i += 64) myhist[i] = 0;
      __syncthreads();
      for (int j = 0; j < 32; j++) {
        unsigned kb = __float_as_uint(sd[j * 256 + tid]);
        if ((kb >> (shift + 8)) == (prefix >> (shift + 8)))
          atomicAdd(&myhist[(kb >> shift) & 255], 1);
      }
    }
    __syncthreads();
    int h = hist4[tid] + hist4[256 + tid] + hist4[512 + tid] + hist4[768 + tid];
    int v = h;
#pragma unroll
    for (int off = 1; off < 64; off <<= 1) {
      int u = __shfl_up(v, off);
      if (lane >= off) v += u;
    }
    if (lane == 63) wsum[wv] = v;
    __syncthreads();
    int base = below;
    for (int w = 0; w < wv; w++) base += wsum[w];
    int excl = base + v - h;
    if (excl < NK && excl + h >= NK) {    // unique crossing thread
      *sprefix = prefix | ((unsigned)tid << shift);
      *sbelow = excl;
    }
    __syncthreads();
    prefix = *sprefix; below = *sbelow;
  }
  const unsigned K32 = prefix;
  if (tid < 2) cnts[tid] = 0;
  __syncthreads();
  for (int j = 0; j < 32; j++) {
    int p = j * 256 + tid;
    unsigned kb = __float_as_uint(sd[p]);
    if (kb < K32) { int q = atomicAdd(&cnts[0], 1); if (q < NK) selA[q] = p; }
    else if (kb == K32) { int q = atomicAdd(&cnts[1], 1); if (q < 256) tib[q] = p; }
  }
  __syncthreads();
  const int n1 = cnts[0] < NK ? cnts[0] : NK;
  int nt = cnts[1]; if (nt > 256) nt = 256;
  if (tid == 0) {
    int need = NK - n1;
    for (int a = 0; a < need; a++) {       // ties -> lowest indices (top_k stable)
      int bj = -1; int bidx = 0x7fffffff;
      for (int j = 0; j < nt; j++) {
        int p = tib[j];
        if (p >= 0 && p < bidx) { bidx = p; bj = j; }
      }
      if (bj >= 0) { selA[n1 + a] = bidx; tib[bj] = -1; }
      else selA[n1 + a] = selA[0];
    }
    float bk = 1e30f; int bp = 0x7fffffff;  // nearest = (min key, min idx)
    for (int j = 0; j < NK; j++) {
      int p = selA[j]; float kk = sd[p];
      if (kk < bk || (kk == bk && p < bp)) { bk = kk; bp = p; }
    }
    *snear_s = bp;
  }
  __syncthreads();
  if (tid < NK) {
    int p = selA[tid];
    qsel_ws[(size_t)cs * NK + tid] = (sd[p] > 0.25f) ? *snear_s : p;
  }
}

// ---------------- MLP + maxpool: small LDS -> high occupancy, few barriers ----------------
__global__ __launch_bounds__(256, 4) void mlp_kernel(
    const float* __restrict__ xyz, const float* __restrict__ points,
    const float* __restrict__ new_xyz, const int* __restrict__ qsel_ws,
    const float* __restrict__ w0, const float* __restrict__ b0, const float* __restrict__ g0,
    const float* __restrict__ bt0, const float* __restrict__ m0, const float* __restrict__ v0,
    const float* __restrict__ w1, const float* __restrict__ b1, const float* __restrict__ g1,
    const float* __restrict__ bt1, const float* __restrict__ m1, const float* __restrict__ v1,
    const float* __restrict__ w2, const float* __restrict__ b2, const float* __restrict__ g2,
    const float* __restrict__ bt2, const float* __restrict__ m2, const float* __restrict__ v2,
    float* __restrict__ out_pts) {
  __shared__ __align__(16) float smem[5536];   // 22144 B
  float* x1   = smem;             // 32*64
  float* x2   = smem + 2048;      // 32*64
  float* pmax = smem + 4096;      // 8*128
  float* gin  = smem + 5120;      // 32*12
  int*   qsl  = (int*)(smem + 5504);  // 32

  const int cs = blockIdx.x;
  const int b = cs >> 11;
  const int tid = threadIdx.x;
  const float cx = new_xyz[cs * 3 + 0], cy = new_xyz[cs * 3 + 1], cz = new_xyz[cs * 3 + 2];
  if (tid < NK) qsl[tid] = qsel_ws[(size_t)cs * NK + tid];
  __syncthreads();
  for (int e = tid; e < 288; e += 256) {
    int k = e / 9, c = e % 9;
    int p = qsl[k];
    float v;
    if (c < 3) {
      float cc = (c == 0) ? cx : (c == 1 ? cy : cz);
      v = fsub(xyz[((size_t)b * NP + p) * 3 + c], cc);
    } else {
      v = points[((size_t)b * NP + p) * 6 + (c - 3)];
    }
    gin[k * 12 + c] = v;
  }
  __syncthreads();
  { // L1: 1 o x 8 k per thread; w0/bn from global (L2-hot)
    int o = tid & 63, k0 = (tid >> 6) * 8;
    float wr[9];
#pragma unroll
    for (int c = 0; c < 9; c++) wr[c] = w0[o * 9 + c];
    float bb = b0[o], bm = m0[o], bg = g0[o], bbt = bt0[o];
    float br = 1.0f / __fsqrt_rn(fadd(v0[o], 1e-5f));
#pragma unroll
    for (int j = 0; j < 8; j++) {
      int k = k0 + j;
      const float4* gq = (const float4*)&gin[k * 12];
      float4 q0 = gq[0], q1 = gq[1], q2 = gq[2];
      float acc = 0.f;
      acc = fmaf(wr[0], q0.x, acc); acc = fmaf(wr[1], q0.y, acc);
      acc = fmaf(wr[2], q0.z, acc); acc = fmaf(wr[3], q0.w, acc);
      acc = fmaf(wr[4], q1.x, acc); acc = fmaf(wr[5], q1.y, acc);
      acc = fmaf(wr[6], q1.z, acc); acc = fmaf(wr[7], q1.w, acc);
      acc = fmaf(wr[8], q2.x, acc);
      float y = fadd(acc, bb);
      y = fadd(fmul(fmul(bg, fsub(y, bm)), br), bbt);
      x1[k * 64 + o] = fmaxf(y, 0.f);
    }
  }
  __syncthreads();
  { // L2: 2 o x 4 k per thread
    int o0 = (tid & 31) * 2, k0 = (tid >> 5) * 4;
    float acc[2][4];
#pragma unroll
    for (int oo = 0; oo < 2; oo++)
#pragma unroll
      for (int kk = 0; kk < 4; kk++) acc[oo][kk] = 0.f;
#pragma unroll
    for (int c4 = 0; c4 < 16; c4++) {
      float4 xq[4];
#pragma unroll
      for (int kk = 0; kk < 4; kk++) xq[kk] = *(const float4*)&x1[(k0 + kk) * 64 + c4 * 4];
#pragma unroll
      for (int oo = 0; oo < 2; oo++) {
        float4 wq = *(const float4*)&w1[(o0 + oo) * 64 + c4 * 4];
#pragma unroll
        for (int kk = 0; kk < 4; kk++) {
          acc[oo][kk] = fmaf(wq.x, xq[kk].x, acc[oo][kk]);
          acc[oo][kk] = fmaf(wq.y, xq[kk].y, acc[oo][kk]);
          acc[oo][kk] = fmaf(wq.z, xq[kk].z, acc[oo][kk]);
          acc[oo][kk] = fmaf(wq.w, xq[kk].w, acc[oo][kk]);
        }
      }
    }
#pragma unroll
    for (int oo = 0; oo < 2; oo++) {
      int o = o0 + oo;
      float bb = b1[o], bm = m1[o], bg = g1[o], bbt = bt1[o];
      float br = 1.0f / __fsqrt_rn(fadd(v1[o], 1e-5f));
#pragma unroll
      for (int kk = 0; kk < 4; kk++) {
        float y = fadd(acc[oo][kk], bb);
        y = fadd(fmul(fmul(bg, fsub(y, bm)), br), bbt);
        x2[(k0 + kk) * 64 + o] = fmaxf(y, 0.f);
      }
    }
  }
  __syncthreads();
  { // L3: 4 ch x 4 k per thread + per-k-group max
    int ch0 = (tid & 31) * 4, k0 = (tid >> 5) * 4, kg = tid >> 5;
    float acc[4][4];
#pragma unroll
    for (int cc = 0; cc < 4; cc++)
#pragma unroll
      for (int kk = 0; kk < 4; kk++) acc[cc][kk] = 0.f;
#pragma unroll
    for (int c4 = 0; c4 < 16; c4++) {
      float4 xq[4];
#pragma unroll
      for (int kk = 0; kk < 4; kk++) xq[kk] = *(const float4*)&x2[(k0 + kk) * 64 + c4 * 4];
#pragma unroll
      for (int cc = 0; cc < 4; cc++) {
        float4 wq = *(const float4*)&w2[(ch0 + cc) * 64 + c4 * 4];
#pragma unroll
        for (int kk = 0; kk < 4; kk++) {
          acc[cc][kk] = fmaf(wq.x, xq[kk].x, acc[cc][kk]);
          acc[cc][kk] = fmaf(wq.y, xq[kk].y, acc[cc][kk]);
          acc[cc][kk] = fmaf(wq.z, xq[kk].z, acc[cc][kk]);
          acc[cc][kk] = fmaf(wq.w, xq[kk].w, acc[cc][kk]);
        }
      }
    }
#pragma unroll
    for (int cc = 0; cc < 4; cc++) {
      int ch = ch0 + cc;
      float bb = b2[ch], bm = m2[ch], bg = g2[ch], bbt = bt2[ch];
      float br = 1.0f / __fsqrt_rn(fadd(v2[ch], 1e-5f));
      float mx = -1e30f;
#pragma unroll
      for (int kk = 0; kk < 4; kk++) {
        float y = fadd(acc[cc][kk], bb);
        y = fadd(fmul(fmul(bg, fsub(y, bm)), br), bbt);
        mx = fmaxf(mx, fmaxf(y, 0.f));
      }
      pmax[kg * 128 + ch] = mx;
    }
  }
  __syncthreads();
  if (tid < 128) {
    float m = pmax[tid];
#pragma unroll
    for (int g = 1; g < 8; g++) m = fmaxf(m, pmax[g * 128 + tid]);
    out_pts[(size_t)cs * 128 + tid] = m;
  }
}

extern "C" void kernel_launch(void* const* d_in, const int* in_sizes, int n_in,
                              void* d_out, int out_size, void* d_ws, size_t ws_size,
                              hipStream_t stream) {
  (void)in_sizes; (void)n_in; (void)out_size; (void)ws_size;
  const float* xyz    = (const float*)d_in[0];
  const float* points = (const float*)d_in[1];
  const float* w0 = (const float*)d_in[2];
  const float* b0 = (const float*)d_in[3];
  const float* g0 = (const float*)d_in[4];
  const float* bt0 = (const float*)d_in[5];
  const float* m0 = (const float*)d_in[6];
  const float* v0 = (const float*)d_in[7];
  const float* w1 = (const float*)d_in[8];
  const float* b1 = (const float*)d_in[9];
  const float* g1 = (const float*)d_in[10];
  const float* bt1 = (const float*)d_in[11];
  const float* m1 = (const float*)d_in[12];
  const float* v1 = (const float*)d_in[13];
  const float* w2 = (const float*)d_in[14];
  const float* b2 = (const float*)d_in[15];
  const float* g2 = (const float*)d_in[16];
  const float* bt2 = (const float*)d_in[17];
  const float* m2 = (const float*)d_in[18];
  const float* v2 = (const float*)d_in[19];

  float* new_xyz = (float*)d_out;                         // 8*2048*3 f32
  float* out_pts = (float*)d_out + (size_t)NB * NS * 3;   // 8*2048*128 f32
  int* qsel_ws = (int*)d_ws;                              // 16384*32 ints = 2 MiB

  fps_kernel<<<NB, 512, 0, stream>>>(xyz, new_xyz);
  ball_kernel<<<NB * NS, 256, 0, stream>>>(xyz, new_xyz, qsel_ws);
  mlp_kernel<<<NB * NS, 256, 0, stream>>>(xyz, points, new_xyz, qsel_ws,
                                          w0, b0, g0, bt0, m0, v0,
                                          w1, b1, g1, bt1, m1, v1,
                                          w2, b2, g2, bt2, m2, v2,
                                          out_pts);
}

// Round 5
// 3650.921 us; speedup vs baseline: 1.0905x; 1.0905x over previous
//
#include <hip/hip_runtime.h>
#include <math.h>

// Forbid fma contraction for every expression in this file (np-matching arithmetic).
#pragma clang fp contract(off)

#define NB 8
#define NP 8192
#define NS 2048
#define NK 32

// Decision-critical f32 ops as raw VALU instructions — cannot be contracted.
// (Used by ball_kernel; fps relies on the file-wide contract(off).)
__device__ __forceinline__ float fsub(float a, float b) {
  float r; asm("v_sub_f32 %0, %1, %2" : "=v"(r) : "v"(a), "v"(b)); return r;
}
__device__ __forceinline__ float fmul(float a, float b) {
  float r; asm("v_mul_f32 %0, %1, %2" : "=v"(r) : "v"(a), "v"(b)); return r;
}
__device__ __forceinline__ float fadd(float a, float b) {
  float r; asm("v_add_f32 %0, %1, %2" : "=v"(r) : "v"(a), "v"(b)); return r;
}

// ---------------- FPS: LDS-resident points + DPP (VALU-pipe) wave reduce ----------------
// R4 post-mortem: LDS staging worked (conflicts ~0) but the u64 shfl reduce
// (~12 ds_bpermute/thread/iter + addr math + 6-level serial chain) CONTENDS
// with the 96 KiB/iter of ds_read_b128 on the one LDS pipe. Fix: do the wave
// reduce entirely on the VALU with DPP row_shr/row_bcast (no LDS traffic):
//   phase 1: wave max of lmax (f32, >=0, zero-fill identity safe)
//   phase 2: among max-holders, lowest gidx == u32 max of ~gidx (>=0, safe)
// Result lands in lane 63 -> readlane -> SGPR broadcast. Bit-identical to the
// u64 (key<<32 | ~idx) max == (max key, lowest index) == np.argmax
// first-occurrence. LDS pipe now carries only the 768-cyc point-read floor.
//
// Distances stay exact: unfused f32 ((dx*dx+dy*dy)+dz*dz under contract(off)).
// Thread t owns points j*2048 + 4t + k; ascending (j,k) => ascending global
// idx, strict '>' scan keeps the lowest index per thread.
__global__ __launch_bounds__(512, 2) void fps_kernel(const float* __restrict__ xyz,
                                                     float* __restrict__ new_xyz) {
  __shared__ __align__(16) float splanes[3 * NP];   // 96 KiB: sx, sy, sz
  __shared__ unsigned long long wbest[2][8];
  float* sx = splanes;
  float* sy = splanes + NP;
  float* sz = splanes + 2 * NP;

  const int b = blockIdx.x;
  const int tid = threadIdx.x;
  const int lane = tid & 63, wv = tid >> 6;
  const float* xb = xyz + (size_t)b * NP * 3;

  // ---- stage global AoS -> LDS SoA (one-time; ~0.1% of kernel) ----
  for (int i = 0; i < 16; i++) {
    int p = tid * 16 + i;
    sx[p] = xb[p * 3 + 0];
    sy[p] = xb[p * 3 + 1];
    sz[p] = xb[p * 3 + 2];
  }
  __syncthreads();

  float dist[16];
#pragma unroll
  for (int i = 0; i < 16; i++) dist[i] = 1e10f;

  float fx = sx[0], fy = sy[0], fz = sz[0];   // farthest = index 0 at t=0
  for (int t = 0; t < NS; t++) {
    if (tid == 0) {
      float* o = new_xyz + ((size_t)b * NS + t) * 3;
      o[0] = fx; o[1] = fy; o[2] = fz;
    }
    const int par = t & 1;
    float lmax = -1.0f; int li = 0;
#define FPS_STEP(lid, xs, ys, zs) { \
      float dx = (xs) - fx; \
      float dy = (ys) - fy; \
      float dz = (zs) - fz; \
      float d = dx * dx + dy * dy + dz * dz;  /* contract(off): 3 mul + 2 add */ \
      float nd = fminf(dist[lid], d); \
      dist[lid] = nd; \
      bool gt = nd > lmax; \
      li = gt ? (lid) : li; \
      lmax = gt ? nd : lmax; }
#pragma unroll
    for (int j = 0; j < 4; j++) {
      const int base = j * 2048 + (tid << 2);
      float4 xv = *(const float4*)&sx[base];
      float4 yv = *(const float4*)&sy[base];
      float4 zv = *(const float4*)&sz[base];
      FPS_STEP(j * 4 + 0, xv.x, yv.x, zv.x)
      FPS_STEP(j * 4 + 1, xv.y, yv.y, zv.y)
      FPS_STEP(j * 4 + 2, xv.z, yv.z, zv.z)
      FPS_STEP(j * 4 + 3, xv.w, yv.w, zv.w)
    }
#undef FPS_STEP
    // ---- wave reduce via DPP (VALU pipe only) ----
    // Phase 1: wave max of lmax. All values >= 0 -> zero-fill identity safe.
    float wm = lmax;
#define DPP_MAXF(ctrl) { int _m = __builtin_amdgcn_update_dpp(0, __float_as_int(wm), (ctrl), 0xf, 0xf, false); \
                         wm = fmaxf(wm, __int_as_float(_m)); }
    DPP_MAXF(0x111) DPP_MAXF(0x112) DPP_MAXF(0x114) DPP_MAXF(0x118)   // row_shr 1,2,4,8
    DPP_MAXF(0x142) DPP_MAXF(0x143)                                    // row_bcast 15,31
#undef DPP_MAXF
    const float wmax = __int_as_float(__builtin_amdgcn_readlane(__float_as_int(wm), 63));
    // Phase 2: lowest global idx among max-holders == u32 max of ~gidx (>=0 safe).
    unsigned gidx = (unsigned)(((li >> 2) << 11) | (tid << 2) | (li & 3));
    unsigned cand = (lmax == wmax) ? ~gidx : 0u;
#define DPP_MAXU(ctrl) { unsigned _m = (unsigned)__builtin_amdgcn_update_dpp(0, (int)cand, (ctrl), 0xf, 0xf, false); \
                         cand = (cand > _m) ? cand : _m; }
    DPP_MAXU(0x111) DPP_MAXU(0x112) DPP_MAXU(0x114) DPP_MAXU(0x118)
    DPP_MAXU(0x142) DPP_MAXU(0x143)
#undef DPP_MAXU
    const unsigned wnidx = (unsigned)__builtin_amdgcn_readlane((int)cand, 63);  // = ~best_idx
    if (lane == 0)
      wbest[par][wv] = ((unsigned long long)__float_as_uint(wmax) << 32)
                     | (unsigned long long)wnidx;
    __syncthreads();                    // single barrier per iteration
    unsigned long long mm = wbest[par][0];
#pragma unroll
    for (int w = 1; w < 8; w++) { unsigned long long c = wbest[par][w]; if (c > mm) mm = c; }
    int bp = (int)(~(unsigned)(mm & 0xFFFFFFFFull));   // global winner index
    // winner coords from LDS (broadcast read, same bits as staged globals)
    fx = sx[bp]; fy = sy[bp]; fz = sz[bp];
    // parity double-buffer: next iteration writes wbest[1-par] — no WAR race
  }
}

// ---------------- Ball query (unchanged semantics) ----------------
// Writes qsel[cs*32..] to global workspace for the MLP kernel.
__global__ __launch_bounds__(256, 4) void ball_kernel(
    const float* __restrict__ xyz, const float* __restrict__ new_xyz,
    int* __restrict__ qsel_ws) {
  __shared__ __align__(16) float smem[9552];
  float* sd         = smem;                      // 8192 keys
  int* hist4        = (int*)(smem + 8192);       // 4 waves x 256 buckets
  int* cnts         = (int*)(smem + 9216);       // 2
  unsigned* sprefix = (unsigned*)(smem + 9218);
  int* sbelow       = (int*)(smem + 9219);
  int* snear_s      = (int*)(smem + 9220);
  int* wsum         = (int*)(smem + 9224);       // 4
  int* selA         = (int*)(smem + 9232);       // 32
  int* tib          = (int*)(smem + 9264);       // 256

  const int cs = blockIdx.x;
  const int b = cs >> 11;
  const int tid = threadIdx.x;
  const int lane = tid & 63, wv = tid >> 6;
  int* myhist = hist4 + wv * 256;
  const float* xb = xyz + (size_t)b * NP * 3;
  const float cx = new_xyz[cs * 3 + 0], cy = new_xyz[cs * 3 + 1], cz = new_xyz[cs * 3 + 2];
  const float Sc = fadd(fadd(fmul(cx, cx), fmul(cy, cy)), fmul(cz, cz));
  for (int i = lane; i < 256; i += 64) myhist[i] = 0;
  for (int j = 0; j < 32; j++) {
    int p = j * 256 + tid;
    float x = xb[p * 3 + 0], y = xb[p * 3 + 1], z = xb[p * 3 + 2];
    float Sn    = fadd(fadd(fmul(x, x), fmul(y, y)), fmul(z, z));
    float inner = fmaf(cz, z, fmaf(cy, y, fmul(cx, x)));
    float d2    = fsub(fadd(Sc, Sn), fmul(2.0f, inner));
    float kk = __fsqrt_rn(fmaxf(d2, 0.0f));
    sd[p] = kk;
    atomicAdd(&myhist[__float_as_uint(kk) >> 24], 1);
  }
  unsigned prefix = 0; int below = 0;
  for (int round = 0; round < 4; round++) {
    const int shift = 24 - 8 * round;
    if (round > 0) {
      for (int i = lane; i < 256; i += 64) myhist[i] = 0;
      __syncthreads();
      for (int j = 0; j < 32; j++) {
        unsigned kb = __float_as_uint(sd[j * 256 + tid]);
        if ((kb >> (shift + 8)) == (prefix >> (shift + 8)))
          atomicAdd(&myhist[(kb >> shift) & 255], 1);
      }
    }
    __syncthreads();
    int h = hist4[tid] + hist4[256 + tid] + hist4[512 + tid] + hist4[768 + tid];
    int v = h;
#pragma unroll
    for (int off = 1; off < 64; off <<= 1) {
      int u = __shfl_up(v, off);
      if (lane >= off) v += u;
    }
    if (lane == 63) wsum[wv] = v;
    __syncthreads();
    int base = below;
    for (int w = 0; w < wv; w++) base += wsum[w];
    int excl = base + v - h;
    if (excl < NK && excl + h >= NK) {    // unique crossing thread
      *sprefix = prefix | ((unsigned)tid << shift);
      *sbelow = excl;
    }
    __syncthreads();
    prefix = *sprefix; below = *sbelow;
  }
  const unsigned K32 = prefix;
  if (tid < 2) cnts[tid] = 0;
  __syncthreads();
  for (int j = 0; j < 32; j++) {
    int p = j * 256 + tid;
    unsigned kb = __float_as_uint(sd[p]);
    if (kb < K32) { int q = atomicAdd(&cnts[0], 1); if (q < NK) selA[q] = p; }
    else if (kb == K32) { int q = atomicAdd(&cnts[1], 1); if (q < 256) tib[q] = p; }
  }
  __syncthreads();
  const int n1 = cnts[0] < NK ? cnts[0] : NK;
  int nt = cnts[1]; if (nt > 256) nt = 256;
  if (tid == 0) {
    int need = NK - n1;
    for (int a = 0; a < need; a++) {       // ties -> lowest indices (top_k stable)
      int bj = -1; int bidx = 0x7fffffff;
      for (int j = 0; j < nt; j++) {
        int p = tib[j];
        if (p >= 0 && p < bidx) { bidx = p; bj = j; }
      }
      if (bj >= 0) { selA[n1 + a] = bidx; tib[bj] = -1; }
      else selA[n1 + a] = selA[0];
    }
    float bk = 1e30f; int bp = 0x7fffffff;  // nearest = (min key, min idx)
    for (int j = 0; j < NK; j++) {
      int p = selA[j]; float kk = sd[p];
      if (kk < bk || (kk == bk && p < bp)) { bk = kk; bp = p; }
    }
    *snear_s = bp;
  }
  __syncthreads();
  if (tid < NK) {
    int p = selA[tid];
    qsel_ws[(size_t)cs * NK + tid] = (sd[p] > 0.25f) ? *snear_s : p;
  }
}

// ---------------- MLP + maxpool: small LDS -> high occupancy, few barriers ----------------
__global__ __launch_bounds__(256, 4) void mlp_kernel(
    const float* __restrict__ xyz, const float* __restrict__ points,
    const float* __restrict__ new_xyz, const int* __restrict__ qsel_ws,
    const float* __restrict__ w0, const float* __restrict__ b0, const float* __restrict__ g0,
    const float* __restrict__ bt0, const float* __restrict__ m0, const float* __restrict__ v0,
    const float* __restrict__ w1, const float* __restrict__ b1, const float* __restrict__ g1,
    const float* __restrict__ bt1, const float* __restrict__ m1, const float* __restrict__ v1,
    const float* __restrict__ w2, const float* __restrict__ b2, const float* __restrict__ g2,
    const float* __restrict__ bt2, const float* __restrict__ m2, const float* __restrict__ v2,
    float* __restrict__ out_pts) {
  __shared__ __align__(16) float smem[5536];   // 22144 B
  float* x1   = smem;             // 32*64
  float* x2   = smem + 2048;      // 32*64
  float* pmax = smem + 4096;      // 8*128
  float* gin  = smem + 5120;      // 32*12
  int*   qsl  = (int*)(smem + 5504);  // 32

  const int cs = blockIdx.x;
  const int b = cs >> 11;
  const int tid = threadIdx.x;
  const float cx = new_xyz[cs * 3 + 0], cy = new_xyz[cs * 3 + 1], cz = new_xyz[cs * 3 + 2];
  if (tid < NK) qsl[tid] = qsel_ws[(size_t)cs * NK + tid];
  __syncthreads();
  for (int e = tid; e < 288; e += 256) {
    int k = e / 9, c = e % 9;
    int p = qsl[k];
    float v;
    if (c < 3) {
      float cc = (c == 0) ? cx : (c == 1 ? cy : cz);
      v = fsub(xyz[((size_t)b * NP + p) * 3 + c], cc);
    } else {
      v = points[((size_t)b * NP + p) * 6 + (c - 3)];
    }
    gin[k * 12 + c] = v;
  }
  __syncthreads();
  { // L1: 1 o x 8 k per thread; w0/bn from global (L2-hot)
    int o = tid & 63, k0 = (tid >> 6) * 8;
    float wr[9];
#pragma unroll
    for (int c = 0; c < 9; c++) wr[c] = w0[o * 9 + c];
    float bb = b0[o], bm = m0[o], bg = g0[o], bbt = bt0[o];
    float br = 1.0f / __fsqrt_rn(fadd(v0[o], 1e-5f));
#pragma unroll
    for (int j = 0; j < 8; j++) {
      int k = k0 + j;
      const float4* gq = (const float4*)&gin[k * 12];
      float4 q0 = gq[0], q1 = gq[1], q2 = gq[2];
      float acc = 0.f;
      acc = fmaf(wr[0], q0.x, acc); acc = fmaf(wr[1], q0.y, acc);
      acc = fmaf(wr[2], q0.z, acc); acc = fmaf(wr[3], q0.w, acc);
      acc = fmaf(wr[4], q1.x, acc); acc = fmaf(wr[5], q1.y, acc);
      acc = fmaf(wr[6], q1.z, acc); acc = fmaf(wr[7], q1.w, acc);
      acc = fmaf(wr[8], q2.x, acc);
      float y = fadd(acc, bb);
      y = fadd(fmul(fmul(bg, fsub(y, bm)), br), bbt);
      x1[k * 64 + o] = fmaxf(y, 0.f);
    }
  }
  __syncthreads();
  { // L2: 2 o x 4 k per thread
    int o0 = (tid & 31) * 2, k0 = (tid >> 5) * 4;
    float acc[2][4];
#pragma unroll
    for (int oo = 0; oo < 2; oo++)
#pragma unroll
      for (int kk = 0; kk < 4; kk++) acc[oo][kk] = 0.f;
#pragma unroll
    for (int c4 = 0; c4 < 16; c4++) {
      float4 xq[4];
#pragma unroll
      for (int kk = 0; kk < 4; kk++) xq[kk] = *(const float4*)&x1[(k0 + kk) * 64 + c4 * 4];
#pragma unroll
      for (int oo = 0; oo < 2; oo++) {
        float4 wq = *(const float4*)&w1[(o0 + oo) * 64 + c4 * 4];
#pragma unroll
        for (int kk = 0; kk < 4; kk++) {
          acc[oo][kk] = fmaf(wq.x, xq[kk].x, acc[oo][kk]);
          acc[oo][kk] = fmaf(wq.y, xq[kk].y, acc[oo][kk]);
          acc[oo][kk] = fmaf(wq.z, xq[kk].z, acc[oo][kk]);
          acc[oo][kk] = fmaf(wq.w, xq[kk].w, acc[oo][kk]);
        }
      }
    }
#pragma unroll
    for (int oo = 0; oo < 2; oo++) {
      int o = o0 + oo;
      float bb = b1[o], bm = m1[o], bg = g1[o], bbt = bt1[o];
      float br = 1.0f / __fsqrt_rn(fadd(v1[o], 1e-5f));
#pragma unroll
      for (int kk = 0; kk < 4; kk++) {
        float y = fadd(acc[oo][kk], bb);
        y = fadd(fmul(fmul(bg, fsub(y, bm)), br), bbt);
        x2[(k0 + kk) * 64 + o] = fmaxf(y, 0.f);
      }
    }
  }
  __syncthreads();
  { // L3: 4 ch x 4 k per thread + per-k-group max
    int ch0 = (tid & 31) * 4, k0 = (tid >> 5) * 4, kg = tid >> 5;
    float acc[4][4];
#pragma unroll
    for (int cc = 0; cc < 4; cc++)
#pragma unroll
      for (int kk = 0; kk < 4; kk++) acc[cc][kk] = 0.f;
#pragma unroll
    for (int c4 = 0; c4 < 16; c4++) {
      float4 xq[4];
#pragma unroll
      for (int kk = 0; kk < 4; kk++) xq[kk] = *(const float4*)&x2[(k0 + kk) * 64 + c4 * 4];
#pragma unroll
      for (int cc = 0; cc < 4; cc++) {
        float4 wq = *(const float4*)&w2[(ch0 + cc) * 64 + c4 * 4];
#pragma unroll
        for (int kk = 0; kk < 4; kk++) {
          acc[cc][kk] = fmaf(wq.x, xq[kk].x, acc[cc][kk]);
          acc[cc][kk] = fmaf(wq.y, xq[kk].y, acc[cc][kk]);
          acc[cc][kk] = fmaf(wq.z, xq[kk].z, acc[cc][kk]);
          acc[cc][kk] = fmaf(wq.w, xq[kk].w, acc[cc][kk]);
        }
      }
    }
#pragma unroll
    for (int cc = 0; cc < 4; cc++) {
      int ch = ch0 + cc;
      float bb = b2[ch], bm = m2[ch], bg = g2[ch], bbt = bt2[ch];
      float br = 1.0f / __fsqrt_rn(fadd(v2[ch], 1e-5f));
      float mx = -1e30f;
#pragma unroll
      for (int kk = 0; kk < 4; kk++) {
        float y = fadd(acc[cc][kk], bb);
        y = fadd(fmul(fmul(bg, fsub(y, bm)), br), bbt);
        mx = fmaxf(mx, fmaxf(y, 0.f));
      }
      pmax[kg * 128 + ch] = mx;
    }
  }
  __syncthreads();
  if (tid < 128) {
    float m = pmax[tid];
#pragma unroll
    for (int g = 1; g < 8; g++) m = fmaxf(m, pmax[g * 128 + tid]);
    out_pts[(size_t)cs * 128 + tid] = m;
  }
}

extern "C" void kernel_launch(void* const* d_in, const int* in_sizes, int n_in,
                              void* d_out, int out_size, void* d_ws, size_t ws_size,
                              hipStream_t stream) {
  (void)in_sizes; (void)n_in; (void)out_size; (void)ws_size;
  const float* xyz    = (const float*)d_in[0];
  const float* points = (const float*)d_in[1];
  const float* w0 = (const float*)d_in[2];
  const float* b0 = (const float*)d_in[3];
  const float* g0 = (const float*)d_in[4];
  const float* bt0 = (const float*)d_in[5];
  const float* m0 = (const float*)d_in[6];
  const float* v0 = (const float*)d_in[7];
  const float* w1 = (const float*)d_in[8];
  const float* b1 = (const float*)d_in[9];
  const float* g1 = (const float*)d_in[10];
  const float* bt1 = (const float*)d_in[11];
  const float* m1 = (const float*)d_in[12];
  const float* v1 = (const float*)d_in[13];
  const float* w2 = (const float*)d_in[14];
  const float* b2 = (const float*)d_in[15];
  const float* g2 = (const float*)d_in[16];
  const float* bt2 = (const float*)d_in[17];
  const float* m2 = (const float*)d_in[18];
  const float* v2 = (const float*)d_in[19];

  float* new_xyz = (float*)d_out;                         // 8*2048*3 f32
  float* out_pts = (float*)d_out + (size_t)NB * NS * 3;   // 8*2048*128 f32
  int* qsel_ws = (int*)d_ws;                              // 16384*32 ints = 2 MiB

  fps_kernel<<<NB, 512, 0, stream>>>(xyz, new_xyz);
  ball_kernel<<<NB * NS, 256, 0, stream>>>(xyz, new_xyz, qsel_ws);
  mlp_kernel<<<NB * NS, 256, 0, stream>>>(xyz, points, new_xyz, qsel_ws,
                                          w0, b0, g0, bt0, m0, v0,
                                          w1, b1, g1, bt1, m1, v1,
                                          w2, b2, g2, bt2, m2, v2,
                                          out_pts);
}

// Round 7
// 3429.277 us; speedup vs baseline: 1.1610x; 1.0646x over previous
//
#include <hip/hip_runtime.h>
#include <math.h>

// Forbid fma contraction for every expression in this file (np-matching arithmetic).
#pragma clang fp contract(off)

#define NB 8
#define NP 8192
#define NS 2048
#define NK 32

// Decision-critical f32 ops as raw VALU instructions — cannot be contracted.
// (Used by ball_kernel; fps relies on the file-wide contract(off).)
__device__ __forceinline__ float fsub(float a, float b) {
  float r; asm("v_sub_f32 %0, %1, %2" : "=v"(r) : "v"(a), "v"(b)); return r;
}
__device__ __forceinline__ float fmul(float a, float b) {
  float r; asm("v_mul_f32 %0, %1, %2" : "=v"(r) : "v"(a), "v"(b)); return r;
}
__device__ __forceinline__ float fadd(float a, float b) {
  float r; asm("v_add_f32 %0, %1, %2" : "=v"(r) : "v"(a), "v"(b)); return r;
}

// ---------------- FPS: REGISTER-resident points (volatile one-shot load) + DPP reduce ----------------
// R5 post-mortem: DPP reduce fixed the reduce-side LDS contention (2600->2270)
// but the per-iter point stream (96 x ds_read_b128/CU/iter ~ 1150 cyc at the
// measured 85 B/cyc b128 rate) remains the binding pipe, and with 2 waves/SIMD
// it does not hide under the ~950-cyc VALU issue. Fix: pull each thread's 16
// points into REGISTERS once via VOLATILE loads. Volatile loads are the one
// thing LLVM can never rematerialize or sink into the loop (rounds 0-3 showed
// plain loads + asm pins all get sunk); any spill pressure goes to the unified
// AGPR file (cheap), not scratch — and ~150 live regs < 256 budget anyway.
// The 2048-iter loop then touches LDS only for wbest + winner-coord broadcast.
// (R6 was an infra failure — container died twice, no counters; this is the
// same experiment resubmitted with loads grouped plane-by-plane.)
//
// Exact semantics preserved: unfused f32 distances ((dx*dx+dy*dy)+dz*dz under
// contract(off)); selection == (max key, lowest global index) == np.argmax
// first-occurrence. Thread t owns points j*2048 + 4t + k; ascending (j,k) =>
// ascending global idx, strict '>' keeps the lowest per thread; DPP phase 2
// (u32 max of ~gidx) keeps the lowest across the wave; u64 scan across waves.
__global__ __launch_bounds__(512, 2) void fps_kernel(const float* __restrict__ xyz,
                                                     float* __restrict__ new_xyz) {
  __shared__ __align__(16) float splanes[3 * NP];   // 96 KiB: sx, sy, sz
  __shared__ unsigned long long wbest[2][8];
  float* sx = splanes;
  float* sy = splanes + NP;
  float* sz = splanes + 2 * NP;

  const int b = blockIdx.x;
  const int tid = threadIdx.x;
  const int lane = tid & 63, wv = tid >> 6;
  const float* xb = xyz + (size_t)b * NP * 3;

  // ---- stage global AoS -> LDS SoA (one-time; also serves winner broadcasts) ----
  for (int i = 0; i < 16; i++) {
    int p = tid * 16 + i;
    sx[p] = xb[p * 3 + 0];
    sy[p] = xb[p * 3 + 1];
    sz[p] = xb[p * 3 + 2];
  }
  __syncthreads();

  // ---- one-shot VOLATILE load of this thread's 16 points into registers ----
  const int tb = tid << 2;
  float rx[16], ry[16], rz[16];
#pragma unroll
  for (int j = 0; j < 4; j++)
#pragma unroll
    for (int k = 0; k < 4; k++)
      rx[j * 4 + k] = *(volatile const float*)&sx[j * 2048 + tb + k];
#pragma unroll
  for (int j = 0; j < 4; j++)
#pragma unroll
    for (int k = 0; k < 4; k++)
      ry[j * 4 + k] = *(volatile const float*)&sy[j * 2048 + tb + k];
#pragma unroll
  for (int j = 0; j < 4; j++)
#pragma unroll
    for (int k = 0; k < 4; k++)
      rz[j * 4 + k] = *(volatile const float*)&sz[j * 2048 + tb + k];

  float dist[16];
#pragma unroll
  for (int i = 0; i < 16; i++) dist[i] = 1e10f;

  float fx = sx[0], fy = sy[0], fz = sz[0];   // farthest = index 0 at t=0
  for (int t = 0; t < NS; t++) {
    if (tid == 0) {
      float* o = new_xyz + ((size_t)b * NS + t) * 3;
      o[0] = fx; o[1] = fy; o[2] = fz;
    }
    const int par = t & 1;
    float lmax = -1.0f; int li = 0;
#pragma unroll
    for (int i = 0; i < 16; i++) {
      float dx = rx[i] - fx;
      float dy = ry[i] - fy;
      float dz = rz[i] - fz;
      float d = dx * dx + dy * dy + dz * dz;  // contract(off): 3 mul + 2 add
      float nd = fminf(dist[i], d);
      dist[i] = nd;
      bool gt = nd > lmax;
      li = gt ? i : li;
      lmax = gt ? nd : lmax;
    }
    // ---- wave reduce via DPP (VALU pipe only) ----
    // Phase 1: wave max of lmax. All values >= 0 -> zero-fill identity safe.
    float wm = lmax;
#define DPP_MAXF(ctrl) { int _m = __builtin_amdgcn_update_dpp(0, __float_as_int(wm), (ctrl), 0xf, 0xf, false); \
                         wm = fmaxf(wm, __int_as_float(_m)); }
    DPP_MAXF(0x111) DPP_MAXF(0x112) DPP_MAXF(0x114) DPP_MAXF(0x118)   // row_shr 1,2,4,8
    DPP_MAXF(0x142) DPP_MAXF(0x143)                                    // row_bcast 15,31
#undef DPP_MAXF
    const float wmax = __int_as_float(__builtin_amdgcn_readlane(__float_as_int(wm), 63));
    // Phase 2: lowest global idx among max-holders == u32 max of ~gidx (>=0 safe).
    unsigned gidx = (unsigned)(((li >> 2) << 11) | (tid << 2) | (li & 3));
    unsigned cand = (lmax == wmax) ? ~gidx : 0u;
#define DPP_MAXU(ctrl) { unsigned _m = (unsigned)__builtin_amdgcn_update_dpp(0, (int)cand, (ctrl), 0xf, 0xf, false); \
                         cand = (cand > _m) ? cand : _m; }
    DPP_MAXU(0x111) DPP_MAXU(0x112) DPP_MAXU(0x114) DPP_MAXU(0x118)
    DPP_MAXU(0x142) DPP_MAXU(0x143)
#undef DPP_MAXU
    const unsigned wnidx = (unsigned)__builtin_amdgcn_readlane((int)cand, 63);  // = ~best_idx
    if (lane == 0)
      wbest[par][wv] = ((unsigned long long)__float_as_uint(wmax) << 32)
                     | (unsigned long long)wnidx;
    __syncthreads();                    // single barrier per iteration
    unsigned long long mm = wbest[par][0];
#pragma unroll
    for (int w = 1; w < 8; w++) { unsigned long long c = wbest[par][w]; if (c > mm) mm = c; }
    int bp = (int)(~(unsigned)(mm & 0xFFFFFFFFull));   // global winner index
    // winner coords from LDS (broadcast read, same bits as staged globals)
    fx = sx[bp]; fy = sy[bp]; fz = sz[bp];
    // parity double-buffer: next iteration writes wbest[1-par] — no WAR race
  }
}

// ---------------- Ball query (unchanged semantics) ----------------
// Writes qsel[cs*32..] to global workspace for the MLP kernel.
__global__ __launch_bounds__(256, 4) void ball_kernel(
    const float* __restrict__ xyz, const float* __restrict__ new_xyz,
    int* __restrict__ qsel_ws) {
  __shared__ __align__(16) float smem[9552];
  float* sd         = smem;                      // 8192 keys
  int* hist4        = (int*)(smem + 8192);       // 4 waves x 256 buckets
  int* cnts         = (int*)(smem + 9216);       // 2
  unsigned* sprefix = (unsigned*)(smem + 9218);
  int* sbelow       = (int*)(smem + 9219);
  int* snear_s      = (int*)(smem + 9220);
  int* wsum         = (int*)(smem + 9224);       // 4
  int* selA         = (int*)(smem + 9232);       // 32
  int* tib          = (int*)(smem + 9264);       // 256

  const int cs = blockIdx.x;
  const int b = cs >> 11;
  const int tid = threadIdx.x;
  const int lane = tid & 63, wv = tid >> 6;
  int* myhist = hist4 + wv * 256;
  const float* xb = xyz + (size_t)b * NP * 3;
  const float cx = new_xyz[cs * 3 + 0], cy = new_xyz[cs * 3 + 1], cz = new_xyz[cs * 3 + 2];
  const float Sc = fadd(fadd(fmul(cx, cx), fmul(cy, cy)), fmul(cz, cz));
  for (int i = lane; i < 256; i += 64) myhist[i] = 0;
  for (int j = 0; j < 32; j++) {
    int p = j * 256 + tid;
    float x = xb[p * 3 + 0], y = xb[p * 3 + 1], z = xb[p * 3 + 2];
    float Sn    = fadd(fadd(fmul(x, x), fmul(y, y)), fmul(z, z));
    float inner = fmaf(cz, z, fmaf(cy, y, fmul(cx, x)));
    float d2    = fsub(fadd(Sc, Sn), fmul(2.0f, inner));
    float kk = __fsqrt_rn(fmaxf(d2, 0.0f));
    sd[p] = kk;
    atomicAdd(&myhist[__float_as_uint(kk) >> 24], 1);
  }
  unsigned prefix = 0; int below = 0;
  for (int round = 0; round < 4; round++) {
    const int shift = 24 - 8 * round;
    if (round > 0) {
      for (int i = lane; i < 256; i += 64) myhist[i] = 0;
      __syncthreads();
      for (int j = 0; j < 32; j++) {
        unsigned kb = __float_as_uint(sd[j * 256 + tid]);
        if ((kb >> (shift + 8)) == (prefix >> (shift + 8)))
          atomicAdd(&myhist[(kb >> shift) & 255], 1);
      }
    }
    __syncthreads();
    int h = hist4[tid] + hist4[256 + tid] + hist4[512 + tid] + hist4[768 + tid];
    int v = h;
#pragma unroll
    for (int off = 1; off < 64; off <<= 1) {
      int u = __shfl_up(v, off);
      if (lane >= off) v += u;
    }
    if (lane == 63) wsum[wv] = v;
    __syncthreads();
    int base = below;
    for (int w = 0; w < wv; w++) base += wsum[w];
    int excl = base + v - h;
    if (excl < NK && excl + h >= NK) {    // unique crossing thread
      *sprefix = prefix | ((unsigned)tid << shift);
      *sbelow = excl;
    }
    __syncthreads();
    prefix = *sprefix; below = *sbelow;
  }
  const unsigned K32 = prefix;
  if (tid < 2) cnts[tid] = 0;
  __syncthreads();
  for (int j = 0; j < 32; j++) {
    int p = j * 256 + tid;
    unsigned kb = __float_as_uint(sd[p]);
    if (kb < K32) { int q = atomicAdd(&cnts[0], 1); if (q < NK) selA[q] = p; }
    else if (kb == K32) { int q = atomicAdd(&cnts[1], 1); if (q < 256) tib[q] = p; }
  }
  __syncthreads();
  const int n1 = cnts[0] < NK ? cnts[0] : NK;
  int nt = cnts[1]; if (nt > 256) nt = 256;
  if (tid == 0) {
    int need = NK - n1;
    for (int a = 0; a < need; a++) {       // ties -> lowest indices (top_k stable)
      int bj = -1; int bidx = 0x7fffffff;
      for (int j = 0; j < nt; j++) {
        int p = tib[j];
        if (p >= 0 && p < bidx) { bidx = p; bj = j; }
      }
      if (bj >= 0) { selA[n1 + a] = bidx; tib[bj] = -1; }
      else selA[n1 + a] = selA[0];
    }
    float bk = 1e30f; int bp = 0x7fffffff;  // nearest = (min key, min idx)
    for (int j = 0; j < NK; j++) {
      int p = selA[j]; float kk = sd[p];
      if (kk < bk || (kk == bk && p < bp)) { bk = kk; bp = p; }
    }
    *snear_s = bp;
  }
  __syncthreads();
  if (tid < NK) {
    int p = selA[tid];
    qsel_ws[(size_t)cs * NK + tid] = (sd[p] > 0.25f) ? *snear_s : p;
  }
}

// ---------------- MLP + maxpool: small LDS -> high occupancy, few barriers ----------------
__global__ __launch_bounds__(256, 4) void mlp_kernel(
    const float* __restrict__ xyz, const float* __restrict__ points,
    const float* __restrict__ new_xyz, const int* __restrict__ qsel_ws,
    const float* __restrict__ w0, const float* __restrict__ b0, const float* __restrict__ g0,
    const float* __restrict__ bt0, const float* __restrict__ m0, const float* __restrict__ v0,
    const float* __restrict__ w1, const float* __restrict__ b1, const float* __restrict__ g1,
    const float* __restrict__ bt1, const float* __restrict__ m1, const float* __restrict__ v1,
    const float* __restrict__ w2, const float* __restrict__ b2, const float* __restrict__ g2,
    const float* __restrict__ bt2, const float* __restrict__ m2, const float* __restrict__ v2,
    float* __restrict__ out_pts) {
  __shared__ __align__(16) float smem[5536];   // 22144 B
  float* x1   = smem;             // 32*64
  float* x2   = smem + 2048;      // 32*64
  float* pmax = smem + 4096;      // 8*128
  float* gin  = smem + 5120;      // 32*12
  int*   qsl  = (int*)(smem + 5504);  // 32

  const int cs = blockIdx.x;
  const int b = cs >> 11;
  const int tid = threadIdx.x;
  const float cx = new_xyz[cs * 3 + 0], cy = new_xyz[cs * 3 + 1], cz = new_xyz[cs * 3 + 2];
  if (tid < NK) qsl[tid] = qsel_ws[(size_t)cs * NK + tid];
  __syncthreads();
  for (int e = tid; e < 288; e += 256) {
    int k = e / 9, c = e % 9;
    int p = qsl[k];
    float v;
    if (c < 3) {
      float cc = (c == 0) ? cx : (c == 1 ? cy : cz);
      v = fsub(xyz[((size_t)b * NP + p) * 3 + c], cc);
    } else {
      v = points[((size_t)b * NP + p) * 6 + (c - 3)];
    }
    gin[k * 12 + c] = v;
  }
  __syncthreads();
  { // L1: 1 o x 8 k per thread; w0/bn from global (L2-hot)
    int o = tid & 63, k0 = (tid >> 6) * 8;
    float wr[9];
#pragma unroll
    for (int c = 0; c < 9; c++) wr[c] = w0[o * 9 + c];
    float bb = b0[o], bm = m0[o], bg = g0[o], bbt = bt0[o];
    float br = 1.0f / __fsqrt_rn(fadd(v0[o], 1e-5f));
#pragma unroll
    for (int j = 0; j < 8; j++) {
      int k = k0 + j;
      const float4* gq = (const float4*)&gin[k * 12];
      float4 q0 = gq[0], q1 = gq[1], q2 = gq[2];
      float acc = 0.f;
      acc = fmaf(wr[0], q0.x, acc); acc = fmaf(wr[1], q0.y, acc);
      acc = fmaf(wr[2], q0.z, acc); acc = fmaf(wr[3], q0.w, acc);
      acc = fmaf(wr[4], q1.x, acc); acc = fmaf(wr[5], q1.y, acc);
      acc = fmaf(wr[6], q1.z, acc); acc = fmaf(wr[7], q1.w, acc);
      acc = fmaf(wr[8], q2.x, acc);
      float y = fadd(acc, bb);
      y = fadd(fmul(fmul(bg, fsub(y, bm)), br), bbt);
      x1[k * 64 + o] = fmaxf(y, 0.f);
    }
  }
  __syncthreads();
  { // L2: 2 o x 4 k per thread
    int o0 = (tid & 31) * 2, k0 = (tid >> 5) * 4;
    float acc[2][4];
#pragma unroll
    for (int oo = 0; oo < 2; oo++)
#pragma unroll
      for (int kk = 0; kk < 4; kk++) acc[oo][kk] = 0.f;
#pragma unroll
    for (int c4 = 0; c4 < 16; c4++) {
      float4 xq[4];
#pragma unroll
      for (int kk = 0; kk < 4; kk++) xq[kk] = *(const float4*)&x1[(k0 + kk) * 64 + c4 * 4];
#pragma unroll
      for (int oo = 0; oo < 2; oo++) {
        float4 wq = *(const float4*)&w1[(o0 + oo) * 64 + c4 * 4];
#pragma unroll
        for (int kk = 0; kk < 4; kk++) {
          acc[oo][kk] = fmaf(wq.x, xq[kk].x, acc[oo][kk]);
          acc[oo][kk] = fmaf(wq.y, xq[kk].y, acc[oo][kk]);
          acc[oo][kk] = fmaf(wq.z, xq[kk].z, acc[oo][kk]);
          acc[oo][kk] = fmaf(wq.w, xq[kk].w, acc[oo][kk]);
        }
      }
    }
#pragma unroll
    for (int oo = 0; oo < 2; oo++) {
      int o = o0 + oo;
      float bb = b1[o], bm = m1[o], bg = g1[o], bbt = bt1[o];
      float br = 1.0f / __fsqrt_rn(fadd(v1[o], 1e-5f));
#pragma unroll
      for (int kk = 0; kk < 4; kk++) {
        float y = fadd(acc[oo][kk], bb);
        y = fadd(fmul(fmul(bg, fsub(y, bm)), br), bbt);
        x2[(k0 + kk) * 64 + o] = fmaxf(y, 0.f);
      }
    }
  }
  __syncthreads();
  { // L3: 4 ch x 4 k per thread + per-k-group max
    int ch0 = (tid & 31) * 4, k0 = (tid >> 5) * 4, kg = tid >> 5;
    float acc[4][4];
#pragma unroll
    for (int cc = 0; cc < 4; cc++)
#pragma unroll
      for (int kk = 0; kk < 4; kk++) acc[cc][kk] = 0.f;
#pragma unroll
    for (int c4 = 0; c4 < 16; c4++) {
      float4 xq[4];
#pragma unroll
      for (int kk = 0; kk < 4; kk++) xq[kk] = *(const float4*)&x2[(k0 + kk) * 64 + c4 * 4];
#pragma unroll
      for (int cc = 0; cc < 4; cc++) {
        float4 wq = *(const float4*)&w2[(ch0 + cc) * 64 + c4 * 4];
#pragma unroll
        for (int kk = 0; kk < 4; kk++) {
          acc[cc][kk] = fmaf(wq.x, xq[kk].x, acc[cc][kk]);
          acc[cc][kk] = fmaf(wq.y, xq[kk].y, acc[cc][kk]);
          acc[cc][kk] = fmaf(wq.z, xq[kk].z, acc[cc][kk]);
          acc[cc][kk] = fmaf(wq.w, xq[kk].w, acc[cc][kk]);
        }
      }
    }
#pragma unroll
    for (int cc = 0; cc < 4; cc++) {
      int ch = ch0 + cc;
      float bb = b2[ch], bm = m2[ch], bg = g2[ch], bbt = bt2[ch];
      float br = 1.0f / __fsqrt_rn(fadd(v2[ch], 1e-5f));
      float mx = -1e30f;
#pragma unroll
      for (int kk = 0; kk < 4; kk++) {
        float y = fadd(acc[cc][kk], bb);
        y = fadd(fmul(fmul(bg, fsub(y, bm)), br), bbt);
        mx = fmaxf(mx, fmaxf(y, 0.f));
      }
      pmax[kg * 128 + ch] = mx;
    }
  }
  __syncthreads();
  if (tid < 128) {
    float m = pmax[tid];
#pragma unroll
    for (int g = 1; g < 8; g++) m = fmaxf(m, pmax[g * 128 + tid]);
    out_pts[(size_t)cs * 128 + tid] = m;
  }
}

extern "C" void kernel_launch(void* const* d_in, const int* in_sizes, int n_in,
                              void* d_out, int out_size, void* d_ws, size_t ws_size,
                              hipStream_t stream) {
  (void)in_sizes; (void)n_in; (void)out_size; (void)ws_size;
  const float* xyz    = (const float*)d_in[0];
  const float* points = (const float*)d_in[1];
  const float* w0 = (const float*)d_in[2];
  const float* b0 = (const float*)d_in[3];
  const float* g0 = (const float*)d_in[4];
  const float* bt0 = (const float*)d_in[5];
  const float* m0 = (const float*)d_in[6];
  const float* v0 = (const float*)d_in[7];
  const float* w1 = (const float*)d_in[8];
  const float* b1 = (const float*)d_in[9];
  const float* g1 = (const float*)d_in[10];
  const float* bt1 = (const float*)d_in[11];
  const float* m1 = (const float*)d_in[12];
  const float* v1 = (const float*)d_in[13];
  const float* w2 = (const float*)d_in[14];
  const float* b2 = (const float*)d_in[15];
  const float* g2 = (const float*)d_in[16];
  const float* bt2 = (const float*)d_in[17];
  const float* m2 = (const float*)d_in[18];
  const float* v2 = (const float*)d_in[19];

  float* new_xyz = (float*)d_out;                         // 8*2048*3 f32
  float* out_pts = (float*)d_out + (size_t)NB * NS * 3;   // 8*2048*128 f32
  int* qsel_ws = (int*)d_ws;                              // 16384*32 ints = 2 MiB

  fps_kernel<<<NB, 512, 0, stream>>>(xyz, new_xyz);
  ball_kernel<<<NB * NS, 256, 0, stream>>>(xyz, new_xyz, qsel_ws);
  mlp_kernel<<<NB * NS, 256, 0, stream>>>(xyz, points, new_xyz, qsel_ws,
                                          w0, b0, g0, bt0, m0, v0,
                                          w1, b1, g1, bt1, m1, v1,
                                          w2, b2, g2, bt2, m2, v2,
                                          out_pts);
}

// Round 8
// 3294.127 us; speedup vs baseline: 1.2087x; 1.0410x over previous
//
#include <hip/hip_runtime.h>
#include <math.h>

// Forbid fma contraction for every expression in this file (np-matching arithmetic).
#pragma clang fp contract(off)

#define NB 8
#define NP 8192
#define NS 2048
#define NK 32

// Decision-critical f32 ops as raw VALU instructions — cannot be contracted.
// (Used by ball_kernel; fps relies on the file-wide contract(off).)
__device__ __forceinline__ float fsub(float a, float b) {
  float r; asm("v_sub_f32 %0, %1, %2" : "=v"(r) : "v"(a), "v"(b)); return r;
}
__device__ __forceinline__ float fmul(float a, float b) {
  float r; asm("v_mul_f32 %0, %1, %2" : "=v"(r) : "v"(a), "v"(b)); return r;
}
__device__ __forceinline__ float fadd(float a, float b) {
  float r; asm("v_add_f32 %0, %1, %2" : "=v"(r) : "v"(a), "v"(b)); return r;
}

// ---------------- FPS: 256 thr x 32 pts in registers + single packed-u64 DPP reduce ----------------
// R7 post-mortem: volatile-LDS residency WORKED (VGPR 88 = full resident set,
// 2270->2031 us). Remaining 2380 cyc/iter = 768 cyc mandatory update issue +
// ~1600 cyc tail (DPP chains, u64 scan, barrier) issued redundantly by 2
// waves/SIMD. Fix: (a) 256 threads x 32 pts — update issue invariant (768
// cyc/SIMD) but tail issues ONCE per SIMD, barrier syncs 4 waves not 8, scan
// is 4 entries not 8; (b) single 6-step DPP chain on the packed u64
// (key<<32 | ~idx) instead of two chained 6-step reductions — same verified
// row_shr/row_bcast movement (R5/R7), zero-fill safe (m > 0 always), halves
// the serial reduce latency. Register cost ~165 VGPR at 1 wave/SIMD — fine.
//
// Exact semantics preserved: unfused f32 distances ((dx*dx+dy*dy)+dz*dz under
// contract(off)); u64 (key<<32 | ~idx) max == (max key, lowest index) ==
// np.argmax first-occurrence. Thread t owns points j*1024 + 4t + k (j=0..7,
// k=0..3): ascending (j,k) => ascending global idx; strict '>' keeps lowest.
__global__ __launch_bounds__(256, 1) void fps_kernel(const float* __restrict__ xyz,
                                                     float* __restrict__ new_xyz) {
  __shared__ __align__(16) float splanes[3 * NP];   // 96 KiB: sx, sy, sz
  __shared__ unsigned long long wbest[2][4];
  float* sx = splanes;
  float* sy = splanes + NP;
  float* sz = splanes + 2 * NP;

  const int b = blockIdx.x;
  const int tid = threadIdx.x;
  const int lane = tid & 63, wv = tid >> 6;
  const float* xb = xyz + (size_t)b * NP * 3;

  // ---- stage global AoS -> LDS SoA (one-time; also serves winner broadcasts) ----
  for (int i = 0; i < 32; i++) {
    int p = tid * 32 + i;
    sx[p] = xb[p * 3 + 0];
    sy[p] = xb[p * 3 + 1];
    sz[p] = xb[p * 3 + 2];
  }
  __syncthreads();

  // ---- one-shot VOLATILE load of this thread's 32 points into registers ----
  // (volatile = cannot be rematerialized/sunk into the loop; R7-verified.)
  const int tb = tid << 2;
  float rx[32], ry[32], rz[32];
#pragma unroll
  for (int j = 0; j < 8; j++)
#pragma unroll
    for (int k = 0; k < 4; k++)
      rx[j * 4 + k] = *(volatile const float*)&sx[j * 1024 + tb + k];
#pragma unroll
  for (int j = 0; j < 8; j++)
#pragma unroll
    for (int k = 0; k < 4; k++)
      ry[j * 4 + k] = *(volatile const float*)&sy[j * 1024 + tb + k];
#pragma unroll
  for (int j = 0; j < 8; j++)
#pragma unroll
    for (int k = 0; k < 4; k++)
      rz[j * 4 + k] = *(volatile const float*)&sz[j * 1024 + tb + k];

  float dist[32];
#pragma unroll
  for (int i = 0; i < 32; i++) dist[i] = 1e10f;

  float fx = sx[0], fy = sy[0], fz = sz[0];   // farthest = index 0 at t=0
  for (int t = 0; t < NS; t++) {
    if (tid == 0) {
      float* o = new_xyz + ((size_t)b * NS + t) * 3;
      o[0] = fx; o[1] = fy; o[2] = fz;
    }
    const int par = t & 1;
    float lmax = -1.0f; int li = 0;
#pragma unroll
    for (int i = 0; i < 32; i++) {
      float dx = rx[i] - fx;
      float dy = ry[i] - fy;
      float dz = rz[i] - fz;
      float d = dx * dx + dy * dy + dz * dz;  // contract(off): 3 mul + 2 add
      float nd = fminf(dist[i], d);
      dist[i] = nd;
      bool gt = nd > lmax;
      li = gt ? i : li;                       // i is an inline const cndmask src
      lmax = gt ? nd : lmax;
    }
    // global idx: p = (li>>2)*1024 + 4*tid + (li&3)
    const unsigned gidx = (unsigned)(((li >> 2) << 10) | (tid << 2) | (li & 3));
    // ---- single packed-u64 DPP wave reduce (VALU pipe only) ----
    // dist >= 0 => key bits unsigned-monotone; ~idx -> lowest idx on key ties.
    // m > 0 always, so the DPP zero-fill is an identity for u64 max.
    unsigned long long m = ((unsigned long long)__float_as_uint(lmax) << 32)
                         | (unsigned long long)(~gidx);
#define DPP_MAX64(ctrl) { \
      unsigned _lo = (unsigned)__builtin_amdgcn_update_dpp(0, (int)(unsigned)m, (ctrl), 0xf, 0xf, false); \
      unsigned _hi = (unsigned)__builtin_amdgcn_update_dpp(0, (int)(unsigned)(m >> 32), (ctrl), 0xf, 0xf, false); \
      unsigned long long _o = ((unsigned long long)_hi << 32) | _lo; \
      if (_o > m) m = _o; }
    DPP_MAX64(0x111) DPP_MAX64(0x112) DPP_MAX64(0x114) DPP_MAX64(0x118)  // row_shr 1,2,4,8
    DPP_MAX64(0x142) DPP_MAX64(0x143)                                    // row_bcast 15,31
#undef DPP_MAX64
    if (lane == 63) wbest[par][wv] = m;       // lane 63 holds the wave total
    __syncthreads();                          // single barrier per iteration
    unsigned long long mm = wbest[par][0];
#pragma unroll
    for (int w = 1; w < 4; w++) { unsigned long long c = wbest[par][w]; if (c > mm) mm = c; }
    int bp = (int)(~(unsigned)(mm & 0xFFFFFFFFull));   // global winner index
    // winner coords from LDS (broadcast read, same bits as staged globals)
    fx = sx[bp]; fy = sy[bp]; fz = sz[bp];
    // parity double-buffer: next iteration writes wbest[1-par] — no WAR race
  }
}

// ---------------- Ball query (unchanged semantics) ----------------
// Writes qsel[cs*32..] to global workspace for the MLP kernel.
__global__ __launch_bounds__(256, 4) void ball_kernel(
    const float* __restrict__ xyz, const float* __restrict__ new_xyz,
    int* __restrict__ qsel_ws) {
  __shared__ __align__(16) float smem[9552];
  float* sd         = smem;                      // 8192 keys
  int* hist4        = (int*)(smem + 8192);       // 4 waves x 256 buckets
  int* cnts         = (int*)(smem + 9216);       // 2
  unsigned* sprefix = (unsigned*)(smem + 9218);
  int* sbelow       = (int*)(smem + 9219);
  int* snear_s      = (int*)(smem + 9220);
  int* wsum         = (int*)(smem + 9224);       // 4
  int* selA         = (int*)(smem + 9232);       // 32
  int* tib          = (int*)(smem + 9264);       // 256

  const int cs = blockIdx.x;
  const int b = cs >> 11;
  const int tid = threadIdx.x;
  const int lane = tid & 63, wv = tid >> 6;
  int* myhist = hist4 + wv * 256;
  const float* xb = xyz + (size_t)b * NP * 3;
  const float cx = new_xyz[cs * 3 + 0], cy = new_xyz[cs * 3 + 1], cz = new_xyz[cs * 3 + 2];
  const float Sc = fadd(fadd(fmul(cx, cx), fmul(cy, cy)), fmul(cz, cz));
  for (int i = lane; i < 256; i += 64) myhist[i] = 0;
  for (int j = 0; j < 32; j++) {
    int p = j * 256 + tid;
    float x = xb[p * 3 + 0], y = xb[p * 3 + 1], z = xb[p * 3 + 2];
    float Sn    = fadd(fadd(fmul(x, x), fmul(y, y)), fmul(z, z));
    float inner = fmaf(cz, z, fmaf(cy, y, fmul(cx, x)));
    float d2    = fsub(fadd(Sc, Sn), fmul(2.0f, inner));
    float kk = __fsqrt_rn(fmaxf(d2, 0.0f));
    sd[p] = kk;
    atomicAdd(&myhist[__float_as_uint(kk) >> 24], 1);
  }
  unsigned prefix = 0; int below = 0;
  for (int round = 0; round < 4; round++) {
    const int shift = 24 - 8 * round;
    if (round > 0) {
      for (int i = lane; i < 256; i += 64) myhist[i] = 0;
      __syncthreads();
      for (int j = 0; j < 32; j++) {
        unsigned kb = __float_as_uint(sd[j * 256 + tid]);
        if ((kb >> (shift + 8)) == (prefix >> (shift + 8)))
          atomicAdd(&myhist[(kb >> shift) & 255], 1);
      }
    }
    __syncthreads();
    int h = hist4[tid] + hist4[256 + tid] + hist4[512 + tid] + hist4[768 + tid];
    int v = h;
#pragma unroll
    for (int off = 1; off < 64; off <<= 1) {
      int u = __shfl_up(v, off);
      if (lane >= off) v += u;
    }
    if (lane == 63) wsum[wv] = v;
    __syncthreads();
    int base = below;
    for (int w = 0; w < wv; w++) base += wsum[w];
    int excl = base + v - h;
    if (excl < NK && excl + h >= NK) {    // unique crossing thread
      *sprefix = prefix | ((unsigned)tid << shift);
      *sbelow = excl;
    }
    __syncthreads();
    prefix = *sprefix; below = *sbelow;
  }
  const unsigned K32 = prefix;
  if (tid < 2) cnts[tid] = 0;
  __syncthreads();
  for (int j = 0; j < 32; j++) {
    int p = j * 256 + tid;
    unsigned kb = __float_as_uint(sd[p]);
    if (kb < K32) { int q = atomicAdd(&cnts[0], 1); if (q < NK) selA[q] = p; }
    else if (kb == K32) { int q = atomicAdd(&cnts[1], 1); if (q < 256) tib[q] = p; }
  }
  __syncthreads();
  const int n1 = cnts[0] < NK ? cnts[0] : NK;
  int nt = cnts[1]; if (nt > 256) nt = 256;
  if (tid == 0) {
    int need = NK - n1;
    for (int a = 0; a < need; a++) {       // ties -> lowest indices (top_k stable)
      int bj = -1; int bidx = 0x7fffffff;
      for (int j = 0; j < nt; j++) {
        int p = tib[j];
        if (p >= 0 && p < bidx) { bidx = p; bj = j; }
      }
      if (bj >= 0) { selA[n1 + a] = bidx; tib[bj] = -1; }
      else selA[n1 + a] = selA[0];
    }
    float bk = 1e30f; int bp = 0x7fffffff;  // nearest = (min key, min idx)
    for (int j = 0; j < NK; j++) {
      int p = selA[j]; float kk = sd[p];
      if (kk < bk || (kk == bk && p < bp)) { bk = kk; bp = p; }
    }
    *snear_s = bp;
  }
  __syncthreads();
  if (tid < NK) {
    int p = selA[tid];
    qsel_ws[(size_t)cs * NK + tid] = (sd[p] > 0.25f) ? *snear_s : p;
  }
}

// ---------------- MLP + maxpool: small LDS -> high occupancy, few barriers ----------------
__global__ __launch_bounds__(256, 4) void mlp_kernel(
    const float* __restrict__ xyz, const float* __restrict__ points,
    const float* __restrict__ new_xyz, const int* __restrict__ qsel_ws,
    const float* __restrict__ w0, const float* __restrict__ b0, const float* __restrict__ g0,
    const float* __restrict__ bt0, const float* __restrict__ m0, const float* __restrict__ v0,
    const float* __restrict__ w1, const float* __restrict__ b1, const float* __restrict__ g1,
    const float* __restrict__ bt1, const float* __restrict__ m1, const float* __restrict__ v1,
    const float* __restrict__ w2, const float* __restrict__ b2, const float* __restrict__ g2,
    const float* __restrict__ bt2, const float* __restrict__ m2, const float* __restrict__ v2,
    float* __restrict__ out_pts) {
  __shared__ __align__(16) float smem[5536];   // 22144 B
  float* x1   = smem;             // 32*64
  float* x2   = smem + 2048;      // 32*64
  float* pmax = smem + 4096;      // 8*128
  float* gin  = smem + 5120;      // 32*12
  int*   qsl  = (int*)(smem + 5504);  // 32

  const int cs = blockIdx.x;
  const int b = cs >> 11;
  const int tid = threadIdx.x;
  const float cx = new_xyz[cs * 3 + 0], cy = new_xyz[cs * 3 + 1], cz = new_xyz[cs * 3 + 2];
  if (tid < NK) qsl[tid] = qsel_ws[(size_t)cs * NK + tid];
  __syncthreads();
  for (int e = tid; e < 288; e += 256) {
    int k = e / 9, c = e % 9;
    int p = qsl[k];
    float v;
    if (c < 3) {
      float cc = (c == 0) ? cx : (c == 1 ? cy : cz);
      v = fsub(xyz[((size_t)b * NP + p) * 3 + c], cc);
    } else {
      v = points[((size_t)b * NP + p) * 6 + (c - 3)];
    }
    gin[k * 12 + c] = v;
  }
  __syncthreads();
  { // L1: 1 o x 8 k per thread; w0/bn from global (L2-hot)
    int o = tid & 63, k0 = (tid >> 6) * 8;
    float wr[9];
#pragma unroll
    for (int c = 0; c < 9; c++) wr[c] = w0[o * 9 + c];
    float bb = b0[o], bm = m0[o], bg = g0[o], bbt = bt0[o];
    float br = 1.0f / __fsqrt_rn(fadd(v0[o], 1e-5f));
#pragma unroll
    for (int j = 0; j < 8; j++) {
      int k = k0 + j;
      const float4* gq = (const float4*)&gin[k * 12];
      float4 q0 = gq[0], q1 = gq[1], q2 = gq[2];
      float acc = 0.f;
      acc = fmaf(wr[0], q0.x, acc); acc = fmaf(wr[1], q0.y, acc);
      acc = fmaf(wr[2], q0.z, acc); acc = fmaf(wr[3], q0.w, acc);
      acc = fmaf(wr[4], q1.x, acc); acc = fmaf(wr[5], q1.y, acc);
      acc = fmaf(wr[6], q1.z, acc); acc = fmaf(wr[7], q1.w, acc);
      acc = fmaf(wr[8], q2.x, acc);
      float y = fadd(acc, bb);
      y = fadd(fmul(fmul(bg, fsub(y, bm)), br), bbt);
      x1[k * 64 + o] = fmaxf(y, 0.f);
    }
  }
  __syncthreads();
  { // L2: 2 o x 4 k per thread
    int o0 = (tid & 31) * 2, k0 = (tid >> 5) * 4;
    float acc[2][4];
#pragma unroll
    for (int oo = 0; oo < 2; oo++)
#pragma unroll
      for (int kk = 0; kk < 4; kk++) acc[oo][kk] = 0.f;
#pragma unroll
    for (int c4 = 0; c4 < 16; c4++) {
      float4 xq[4];
#pragma unroll
      for (int kk = 0; kk < 4; kk++) xq[kk] = *(const float4*)&x1[(k0 + kk) * 64 + c4 * 4];
#pragma unroll
      for (int oo = 0; oo < 2; oo++) {
        float4 wq = *(const float4*)&w1[(o0 + oo) * 64 + c4 * 4];
#pragma unroll
        for (int kk = 0; kk < 4; kk++) {
          acc[oo][kk] = fmaf(wq.x, xq[kk].x, acc[oo][kk]);
          acc[oo][kk] = fmaf(wq.y, xq[kk].y, acc[oo][kk]);
          acc[oo][kk] = fmaf(wq.z, xq[kk].z, acc[oo][kk]);
          acc[oo][kk] = fmaf(wq.w, xq[kk].w, acc[oo][kk]);
        }
      }
    }
#pragma unroll
    for (int oo = 0; oo < 2; oo++) {
      int o = o0 + oo;
      float bb = b1[o], bm = m1[o], bg = g1[o], bbt = bt1[o];
      float br = 1.0f / __fsqrt_rn(fadd(v1[o], 1e-5f));
#pragma unroll
      for (int kk = 0; kk < 4; kk++) {
        float y = fadd(acc[oo][kk], bb);
        y = fadd(fmul(fmul(bg, fsub(y, bm)), br), bbt);
        x2[(k0 + kk) * 64 + o] = fmaxf(y, 0.f);
      }
    }
  }
  __syncthreads();
  { // L3: 4 ch x 4 k per thread + per-k-group max
    int ch0 = (tid & 31) * 4, k0 = (tid >> 5) * 4, kg = tid >> 5;
    float acc[4][4];
#pragma unroll
    for (int cc = 0; cc < 4; cc++)
#pragma unroll
      for (int kk = 0; kk < 4; kk++) acc[cc][kk] = 0.f;
#pragma unroll
    for (int c4 = 0; c4 < 16; c4++) {
      float4 xq[4];
#pragma unroll
      for (int kk = 0; kk < 4; kk++) xq[kk] = *(const float4*)&x2[(k0 + kk) * 64 + c4 * 4];
#pragma unroll
      for (int cc = 0; cc < 4; cc++) {
        float4 wq = *(const float4*)&w2[(ch0 + cc) * 64 + c4 * 4];
#pragma unroll
        for (int kk = 0; kk < 4; kk++) {
          acc[cc][kk] = fmaf(wq.x, xq[kk].x, acc[cc][kk]);
          acc[cc][kk] = fmaf(wq.y, xq[kk].y, acc[cc][kk]);
          acc[cc][kk] = fmaf(wq.z, xq[kk].z, acc[cc][kk]);
          acc[cc][kk] = fmaf(wq.w, xq[kk].w, acc[cc][kk]);
        }
      }
    }
#pragma unroll
    for (int cc = 0; cc < 4; cc++) {
      int ch = ch0 + cc;
      float bb = b2[ch], bm = m2[ch], bg = g2[ch], bbt = bt2[ch];
      float br = 1.0f / __fsqrt_rn(fadd(v2[ch], 1e-5f));
      float mx = -1e30f;
#pragma unroll
      for (int kk = 0; kk < 4; kk++) {
        float y = fadd(acc[cc][kk], bb);
        y = fadd(fmul(fmul(bg, fsub(y, bm)), br), bbt);
        mx = fmaxf(mx, fmaxf(y, 0.f));
      }
      pmax[kg * 128 + ch] = mx;
    }
  }
  __syncthreads();
  if (tid < 128) {
    float m = pmax[tid];
#pragma unroll
    for (int g = 1; g < 8; g++) m = fmaxf(m, pmax[g * 128 + tid]);
    out_pts[(size_t)cs * 128 + tid] = m;
  }
}

extern "C" void kernel_launch(void* const* d_in, const int* in_sizes, int n_in,
                              void* d_out, int out_size, void* d_ws, size_t ws_size,
                              hipStream_t stream) {
  (void)in_sizes; (void)n_in; (void)out_size; (void)ws_size;
  const float* xyz    = (const float*)d_in[0];
  const float* points = (const float*)d_in[1];
  const float* w0 = (const float*)d_in[2];
  const float* b0 = (const float*)d_in[3];
  const float* g0 = (const float*)d_in[4];
  const float* bt0 = (const float*)d_in[5];
  const float* m0 = (const float*)d_in[6];
  const float* v0 = (const float*)d_in[7];
  const float* w1 = (const float*)d_in[8];
  const float* b1 = (const float*)d_in[9];
  const float* g1 = (const float*)d_in[10];
  const float* bt1 = (const float*)d_in[11];
  const float* m1 = (const float*)d_in[12];
  const float* v1 = (const float*)d_in[13];
  const float* w2 = (const float*)d_in[14];
  const float* b2 = (const float*)d_in[15];
  const float* g2 = (const float*)d_in[16];
  const float* bt2 = (const float*)d_in[17];
  const float* m2 = (const float*)d_in[18];
  const float* v2 = (const float*)d_in[19];

  float* new_xyz = (float*)d_out;                         // 8*2048*3 f32
  float* out_pts = (float*)d_out + (size_t)NB * NS * 3;   // 8*2048*128 f32
  int* qsel_ws = (int*)d_ws;                              // 16384*32 ints = 2 MiB

  fps_kernel<<<NB, 256, 0, stream>>>(xyz, new_xyz);
  ball_kernel<<<NB * NS, 256, 0, stream>>>(xyz, new_xyz, qsel_ws);
  mlp_kernel<<<NB * NS, 256, 0, stream>>>(xyz, points, new_xyz, qsel_ws,
                                          w0, b0, g0, bt0, m0, v0,
                                          w1, b1, g1, bt1, m1, v1,
                                          w2, b2, g2, bt2, m2, v2,
                                          out_pts);
}

// Round 9
// 3222.411 us; speedup vs baseline: 1.2356x; 1.0223x over previous
//
#include <hip/hip_runtime.h>
#include <math.h>

// Forbid fma contraction for every expression in this file (np-matching arithmetic).
#pragma clang fp contract(off)

#define NB 8
#define NP 8192
#define NS 2048
#define NK 32

// Decision-critical f32 ops as raw VALU instructions — cannot be contracted.
// (Used by ball_kernel; fps relies on the file-wide contract(off).)
__device__ __forceinline__ float fsub(float a, float b) {
  float r; asm("v_sub_f32 %0, %1, %2" : "=v"(r) : "v"(a), "v"(b)); return r;
}
__device__ __forceinline__ float fmul(float a, float b) {
  float r; asm("v_mul_f32 %0, %1, %2" : "=v"(r) : "v"(a), "v"(b)); return r;
}
__device__ __forceinline__ float fadd(float a, float b) {
  float r; asm("v_add_f32 %0, %1, %2" : "=v"(r) : "v"(a), "v"(b)); return r;
}

// ---------------- FPS: 256 thr x 32 pts in registers + single packed-u64 DPP reduce ----------------
// (R8-verified at ~1898 us; frozen this round. See R7/R8 notes: volatile-LDS
// register residency + single packed-u64 DPP chain + 4-wave tail.)
__global__ __launch_bounds__(256, 1) void fps_kernel(const float* __restrict__ xyz,
                                                     float* __restrict__ new_xyz) {
  __shared__ __align__(16) float splanes[3 * NP];   // 96 KiB: sx, sy, sz
  __shared__ unsigned long long wbest[2][4];
  float* sx = splanes;
  float* sy = splanes + NP;
  float* sz = splanes + 2 * NP;

  const int b = blockIdx.x;
  const int tid = threadIdx.x;
  const int lane = tid & 63, wv = tid >> 6;
  const float* xb = xyz + (size_t)b * NP * 3;

  // ---- stage global AoS -> LDS SoA (one-time; also serves winner broadcasts) ----
  for (int i = 0; i < 32; i++) {
    int p = tid * 32 + i;
    sx[p] = xb[p * 3 + 0];
    sy[p] = xb[p * 3 + 1];
    sz[p] = xb[p * 3 + 2];
  }
  __syncthreads();

  // ---- one-shot VOLATILE load of this thread's 32 points into registers ----
  // (volatile = cannot be rematerialized/sunk into the loop; R7-verified.)
  const int tb = tid << 2;
  float rx[32], ry[32], rz[32];
#pragma unroll
  for (int j = 0; j < 8; j++)
#pragma unroll
    for (int k = 0; k < 4; k++)
      rx[j * 4 + k] = *(volatile const float*)&sx[j * 1024 + tb + k];
#pragma unroll
  for (int j = 0; j < 8; j++)
#pragma unroll
    for (int k = 0; k < 4; k++)
      ry[j * 4 + k] = *(volatile const float*)&sy[j * 1024 + tb + k];
#pragma unroll
  for (int j = 0; j < 8; j++)
#pragma unroll
    for (int k = 0; k < 4; k++)
      rz[j * 4 + k] = *(volatile const float*)&sz[j * 1024 + tb + k];

  float dist[32];
#pragma unroll
  for (int i = 0; i < 32; i++) dist[i] = 1e10f;

  float fx = sx[0], fy = sy[0], fz = sz[0];   // farthest = index 0 at t=0
  for (int t = 0; t < NS; t++) {
    if (tid == 0) {
      float* o = new_xyz + ((size_t)b * NS + t) * 3;
      o[0] = fx; o[1] = fy; o[2] = fz;
    }
    const int par = t & 1;
    float lmax = -1.0f; int li = 0;
#pragma unroll
    for (int i = 0; i < 32; i++) {
      float dx = rx[i] - fx;
      float dy = ry[i] - fy;
      float dz = rz[i] - fz;
      float d = dx * dx + dy * dy + dz * dz;  // contract(off): 3 mul + 2 add
      float nd = fminf(dist[i], d);
      dist[i] = nd;
      bool gt = nd > lmax;
      li = gt ? i : li;                       // i is an inline const cndmask src
      lmax = gt ? nd : lmax;
    }
    // global idx: p = (li>>2)*1024 + 4*tid + (li&3)
    const unsigned gidx = (unsigned)(((li >> 2) << 10) | (tid << 2) | (li & 3));
    // ---- single packed-u64 DPP wave reduce (VALU pipe only) ----
    unsigned long long m = ((unsigned long long)__float_as_uint(lmax) << 32)
                         | (unsigned long long)(~gidx);
#define DPP_MAX64(ctrl) { \
      unsigned _lo = (unsigned)__builtin_amdgcn_update_dpp(0, (int)(unsigned)m, (ctrl), 0xf, 0xf, false); \
      unsigned _hi = (unsigned)__builtin_amdgcn_update_dpp(0, (int)(unsigned)(m >> 32), (ctrl), 0xf, 0xf, false); \
      unsigned long long _o = ((unsigned long long)_hi << 32) | _lo; \
      if (_o > m) m = _o; }
    DPP_MAX64(0x111) DPP_MAX64(0x112) DPP_MAX64(0x114) DPP_MAX64(0x118)  // row_shr 1,2,4,8
    DPP_MAX64(0x142) DPP_MAX64(0x143)                                    // row_bcast 15,31
#undef DPP_MAX64
    if (lane == 63) wbest[par][wv] = m;       // lane 63 holds the wave total
    __syncthreads();                          // single barrier per iteration
    unsigned long long mm = wbest[par][0];
#pragma unroll
    for (int w = 1; w < 4; w++) { unsigned long long c = wbest[par][w]; if (c > mm) mm = c; }
    int bp = (int)(~(unsigned)(mm & 0xFFFFFFFFull));   // global winner index
    // winner coords from LDS (broadcast read, same bits as staged globals)
    fx = sx[bp]; fy = sy[bp]; fz = sz[bp];
    // parity double-buffer: next iteration writes wbest[1-par] — no WAR race
  }
}

// ---------------- Ball query: ballot-aggregated LDS atomics ----------------
// R8 analysis: keys kk in [0, sqrt(3)] => radix round-0 bucket (float bits
// [31:24]) maps [0.5,2.0) to 0x3F and [0.25,0.5) to 0x3E — ~90% of the 8192
// atomicAdds hit 1-2 LDS addresses (30-60-way same-address serialization;
// SQ_LDS_BANK_CONFLICT 9.4e7/dispatch ~ 154 us/CU). Fix: (a) round-0 histogram
// via ballot-combining (one atomic per DISTINCT bucket per wave, counts
// identical); (b) collect pass via ballot-rank (one atomic per wave per
// predicate; q = base+rank). Selection is set-semantic: radix invariant gives
// count(kb<K32) <= 31 < NK so every below-key lands in selA regardless of
// order; tie-fill takes lowest indices from the tib SET; nearest = (min key,
// min idx) over the set; downstream maxpool is order-invariant. Outputs
// bit-identical. Rounds 1-3 keep plain atomics (sparse lanes, mantissa-spread
// buckets -> low conflict).
__global__ __launch_bounds__(256, 4) void ball_kernel(
    const float* __restrict__ xyz, const float* __restrict__ new_xyz,
    int* __restrict__ qsel_ws) {
  __shared__ __align__(16) float smem[9552];
  float* sd         = smem;                      // 8192 keys
  int* hist4        = (int*)(smem + 8192);       // 4 waves x 256 buckets
  int* cnts         = (int*)(smem + 9216);       // 2
  unsigned* sprefix = (unsigned*)(smem + 9218);
  int* sbelow       = (int*)(smem + 9219);
  int* snear_s      = (int*)(smem + 9220);
  int* wsum         = (int*)(smem + 9224);       // 4
  int* selA         = (int*)(smem + 9232);       // 32
  int* tib          = (int*)(smem + 9264);       // 256

  const int cs = blockIdx.x;
  const int b = cs >> 11;
  const int tid = threadIdx.x;
  const int lane = tid & 63, wv = tid >> 6;
  int* myhist = hist4 + wv * 256;
  const float* xb = xyz + (size_t)b * NP * 3;
  const float cx = new_xyz[cs * 3 + 0], cy = new_xyz[cs * 3 + 1], cz = new_xyz[cs * 3 + 2];
  const float Sc = fadd(fadd(fmul(cx, cx), fmul(cy, cy)), fmul(cz, cz));
  const unsigned long long lmask_lt = (lane == 0) ? 0ull : (~0ull >> (64 - lane));
  for (int i = lane; i < 256; i += 64) myhist[i] = 0;
  for (int j = 0; j < 32; j++) {
    int p = j * 256 + tid;
    float x = xb[p * 3 + 0], y = xb[p * 3 + 1], z = xb[p * 3 + 2];
    float Sn    = fadd(fadd(fmul(x, x), fmul(y, y)), fmul(z, z));
    float inner = fmaf(cz, z, fmaf(cy, y, fmul(cx, x)));
    float d2    = fsub(fadd(Sc, Sn), fmul(2.0f, inner));
    float kk = __fsqrt_rn(fmaxf(d2, 0.0f));
    sd[p] = kk;
    // ballot-combined histogram: one atomic per distinct bucket in the wave
    unsigned bucket = __float_as_uint(kk) >> 24;
    unsigned long long rem = __ballot(1);
    while (rem) {
      int leader = (int)__ffsll((unsigned long long)rem) - 1;
      unsigned lb = (unsigned)__shfl((int)bucket, leader);
      unsigned long long mk = __ballot(bucket == lb);
      if (lane == leader) atomicAdd(&myhist[lb], (int)__popcll(mk));
      rem &= ~mk;
    }
  }
  unsigned prefix = 0; int below = 0;
  for (int round = 0; round < 4; round++) {
    const int shift = 24 - 8 * round;
    if (round > 0) {
      for (int i = lane; i < 256; i += 64) myhist[i] = 0;
      __syncthreads();
      for (int j = 0; j < 32; j++) {
        unsigned kb = __float_as_uint(sd[j * 256 + tid]);
        if ((kb >> (shift + 8)) == (prefix >> (shift + 8)))
          atomicAdd(&myhist[(kb >> shift) & 255], 1);
      }
    }
    __syncthreads();
    int h = hist4[tid] + hist4[256 + tid] + hist4[512 + tid] + hist4[768 + tid];
    int v = h;
#pragma unroll
    for (int off = 1; off < 64; off <<= 1) {
      int u = __shfl_up(v, off);
      if (lane >= off) v += u;
    }
    if (lane == 63) wsum[wv] = v;
    __syncthreads();
    int base = below;
    for (int w = 0; w < wv; w++) base += wsum[w];
    int excl = base + v - h;
    if (excl < NK && excl + h >= NK) {    // unique crossing thread
      *sprefix = prefix | ((unsigned)tid << shift);
      *sbelow = excl;
    }
    __syncthreads();
    prefix = *sprefix; below = *sbelow;
  }
  const unsigned K32 = prefix;
  if (tid < 2) cnts[tid] = 0;
  __syncthreads();
  for (int j = 0; j < 32; j++) {
    int p = j * 256 + tid;
    unsigned kb = __float_as_uint(sd[p]);
    bool isA = (kb < K32);
    bool isT = (kb == K32);
    // ballot-ranked allocation: one atomic per wave per predicate
    unsigned long long mA = __ballot(isA);
    if (isA) {
      int leader = (int)__ffsll(mA) - 1;
      int basev = 0;
      if (lane == leader) basev = atomicAdd(&cnts[0], (int)__popcll(mA));
      basev = __shfl(basev, leader);
      int q = basev + (int)__popcll(mA & lmask_lt);
      if (q < NK) selA[q] = p;
    }
    unsigned long long mT = __ballot(isT);
    if (isT) {
      int leader = (int)__ffsll(mT) - 1;
      int basev = 0;
      if (lane == leader) basev = atomicAdd(&cnts[1], (int)__popcll(mT));
      basev = __shfl(basev, leader);
      int q = basev + (int)__popcll(mT & lmask_lt);
      if (q < 256) tib[q] = p;
    }
  }
  __syncthreads();
  const int n1 = cnts[0] < NK ? cnts[0] : NK;
  int nt = cnts[1]; if (nt > 256) nt = 256;
  if (tid == 0) {
    int need = NK - n1;
    for (int a = 0; a < need; a++) {       // ties -> lowest indices (top_k stable)
      int bj = -1; int bidx = 0x7fffffff;
      for (int j = 0; j < nt; j++) {
        int p = tib[j];
        if (p >= 0 && p < bidx) { bidx = p; bj = j; }
      }
      if (bj >= 0) { selA[n1 + a] = bidx; tib[bj] = -1; }
      else selA[n1 + a] = selA[0];
    }
    float bk = 1e30f; int bp = 0x7fffffff;  // nearest = (min key, min idx)
    for (int j = 0; j < NK; j++) {
      int p = selA[j]; float kk = sd[p];
      if (kk < bk || (kk == bk && p < bp)) { bk = kk; bp = p; }
    }
    *snear_s = bp;
  }
  __syncthreads();
  if (tid < NK) {
    int p = selA[tid];
    qsel_ws[(size_t)cs * NK + tid] = (sd[p] > 0.25f) ? *snear_s : p;
  }
}

// ---------------- MLP + maxpool: small LDS -> high occupancy, few barriers ----------------
__global__ __launch_bounds__(256, 4) void mlp_kernel(
    const float* __restrict__ xyz, const float* __restrict__ points,
    const float* __restrict__ new_xyz, const int* __restrict__ qsel_ws,
    const float* __restrict__ w0, const float* __restrict__ b0, const float* __restrict__ g0,
    const float* __restrict__ bt0, const float* __restrict__ m0, const float* __restrict__ v0,
    const float* __restrict__ w1, const float* __restrict__ b1, const float* __restrict__ g1,
    const float* __restrict__ bt1, const float* __restrict__ m1, const float* __restrict__ v1,
    const float* __restrict__ w2, const float* __restrict__ b2, const float* __restrict__ g2,
    const float* __restrict__ bt2, const float* __restrict__ m2, const float* __restrict__ v2,
    float* __restrict__ out_pts) {
  __shared__ __align__(16) float smem[5536];   // 22144 B
  float* x1   = smem;             // 32*64
  float* x2   = smem + 2048;      // 32*64
  float* pmax = smem + 4096;      // 8*128
  float* gin  = smem + 5120;      // 32*12
  int*   qsl  = (int*)(smem + 5504);  // 32

  const int cs = blockIdx.x;
  const int b = cs >> 11;
  const int tid = threadIdx.x;
  const float cx = new_xyz[cs * 3 + 0], cy = new_xyz[cs * 3 + 1], cz = new_xyz[cs * 3 + 2];
  if (tid < NK) qsl[tid] = qsel_ws[(size_t)cs * NK + tid];
  __syncthreads();
  for (int e = tid; e < 288; e += 256) {
    int k = e / 9, c = e % 9;
    int p = qsl[k];
    float v;
    if (c < 3) {
      float cc = (c == 0) ? cx : (c == 1 ? cy : cz);
      v = fsub(xyz[((size_t)b * NP + p) * 3 + c], cc);
    } else {
      v = points[((size_t)b * NP + p) * 6 + (c - 3)];
    }
    gin[k * 12 + c] = v;
  }
  __syncthreads();
  { // L1: 1 o x 8 k per thread; w0/bn from global (L2-hot)
    int o = tid & 63, k0 = (tid >> 6) * 8;
    float wr[9];
#pragma unroll
    for (int c = 0; c < 9; c++) wr[c] = w0[o * 9 + c];
    float bb = b0[o], bm = m0[o], bg = g0[o], bbt = bt0[o];
    float br = 1.0f / __fsqrt_rn(fadd(v0[o], 1e-5f));
#pragma unroll
    for (int j = 0; j < 8; j++) {
      int k = k0 + j;
      const float4* gq = (const float4*)&gin[k * 12];
      float4 q0 = gq[0], q1 = gq[1], q2 = gq[2];
      float acc = 0.f;
      acc = fmaf(wr[0], q0.x, acc); acc = fmaf(wr[1], q0.y, acc);
      acc = fmaf(wr[2], q0.z, acc); acc = fmaf(wr[3], q0.w, acc);
      acc = fmaf(wr[4], q1.x, acc); acc = fmaf(wr[5], q1.y, acc);
      acc = fmaf(wr[6], q1.z, acc); acc = fmaf(wr[7], q1.w, acc);
      acc = fmaf(wr[8], q2.x, acc);
      float y = fadd(acc, bb);
      y = fadd(fmul(fmul(bg, fsub(y, bm)), br), bbt);
      x1[k * 64 + o] = fmaxf(y, 0.f);
    }
  }
  __syncthreads();
  { // L2: 2 o x 4 k per thread
    int o0 = (tid & 31) * 2, k0 = (tid >> 5) * 4;
    float acc[2][4];
#pragma unroll
    for (int oo = 0; oo < 2; oo++)
#pragma unroll
      for (int kk = 0; kk < 4; kk++) acc[oo][kk] = 0.f;
#pragma unroll
    for (int c4 = 0; c4 < 16; c4++) {
      float4 xq[4];
#pragma unroll
      for (int kk = 0; kk < 4; kk++) xq[kk] = *(const float4*)&x1[(k0 + kk) * 64 + c4 * 4];
#pragma unroll
      for (int oo = 0; oo < 2; oo++) {
        float4 wq = *(const float4*)&w1[(o0 + oo) * 64 + c4 * 4];
#pragma unroll
        for (int kk = 0; kk < 4; kk++) {
          acc[oo][kk] = fmaf(wq.x, xq[kk].x, acc[oo][kk]);
          acc[oo][kk] = fmaf(wq.y, xq[kk].y, acc[oo][kk]);
          acc[oo][kk] = fmaf(wq.z, xq[kk].z, acc[oo][kk]);
          acc[oo][kk] = fmaf(wq.w, xq[kk].w, acc[oo][kk]);
        }
      }
    }
#pragma unroll
    for (int oo = 0; oo < 2; oo++) {
      int o = o0 + oo;
      float bb = b1[o], bm = m1[o], bg = g1[o], bbt = bt1[o];
      float br = 1.0f / __fsqrt_rn(fadd(v1[o], 1e-5f));
#pragma unroll
      for (int kk = 0; kk < 4; kk++) {
        float y = fadd(acc[oo][kk], bb);
        y = fadd(fmul(fmul(bg, fsub(y, bm)), br), bbt);
        x2[(k0 + kk) * 64 + o] = fmaxf(y, 0.f);
      }
    }
  }
  __syncthreads();
  { // L3: 4 ch x 4 k per thread + per-k-group max
    int ch0 = (tid & 31) * 4, k0 = (tid >> 5) * 4, kg = tid >> 5;
    float acc[4][4];
#pragma unroll
    for (int cc = 0; cc < 4; cc++)
#pragma unroll
      for (int kk = 0; kk < 4; kk++) acc[cc][kk] = 0.f;
#pragma unroll
    for (int c4 = 0; c4 < 16; c4++) {
      float4 xq[4];
#pragma unroll
      for (int kk = 0; kk < 4; kk++) xq[kk] = *(const float4*)&x2[(k0 + kk) * 64 + c4 * 4];
#pragma unroll
      for (int cc = 0; cc < 4; cc++) {
        float4 wq = *(const float4*)&w2[(ch0 + cc) * 64 + c4 * 4];
#pragma unroll
        for (int kk = 0; kk < 4; kk++) {
          acc[cc][kk] = fmaf(wq.x, xq[kk].x, acc[cc][kk]);
          acc[cc][kk] = fmaf(wq.y, xq[kk].y, acc[cc][kk]);
          acc[cc][kk] = fmaf(wq.z, xq[kk].z, acc[cc][kk]);
          acc[cc][kk] = fmaf(wq.w, xq[kk].w, acc[cc][kk]);
        }
      }
    }
#pragma unroll
    for (int cc = 0; cc < 4; cc++) {
      int ch = ch0 + cc;
      float bb = b2[ch], bm = m2[ch], bg = g2[ch], bbt = bt2[ch];
      float br = 1.0f / __fsqrt_rn(fadd(v2[ch], 1e-5f));
      float mx = -1e30f;
#pragma unroll
      for (int kk = 0; kk < 4; kk++) {
        float y = fadd(acc[cc][kk], bb);
        y = fadd(fmul(fmul(bg, fsub(y, bm)), br), bbt);
        mx = fmaxf(mx, fmaxf(y, 0.f));
      }
      pmax[kg * 128 + ch] = mx;
    }
  }
  __syncthreads();
  if (tid < 128) {
    float m = pmax[tid];
#pragma unroll
    for (int g = 1; g < 8; g++) m = fmaxf(m, pmax[g * 128 + tid]);
    out_pts[(size_t)cs * 128 + tid] = m;
  }
}

extern "C" void kernel_launch(void* const* d_in, const int* in_sizes, int n_in,
                              void* d_out, int out_size, void* d_ws, size_t ws_size,
                              hipStream_t stream) {
  (void)in_sizes; (void)n_in; (void)out_size; (void)ws_size;
  const float* xyz    = (const float*)d_in[0];
  const float* points = (const float*)d_in[1];
  const float* w0 = (const float*)d_in[2];
  const float* b0 = (const float*)d_in[3];
  const float* g0 = (const float*)d_in[4];
  const float* bt0 = (const float*)d_in[5];
  const float* m0 = (const float*)d_in[6];
  const float* v0 = (const float*)d_in[7];
  const float* w1 = (const float*)d_in[8];
  const float* b1 = (const float*)d_in[9];
  const float* g1 = (const float*)d_in[10];
  const float* bt1 = (const float*)d_in[11];
  const float* m1 = (const float*)d_in[12];
  const float* v1 = (const float*)d_in[13];
  const float* w2 = (const float*)d_in[14];
  const float* b2 = (const float*)d_in[15];
  const float* g2 = (const float*)d_in[16];
  const float* bt2 = (const float*)d_in[17];
  const float* m2 = (const float*)d_in[18];
  const float* v2 = (const float*)d_in[19];

  float* new_xyz = (float*)d_out;                         // 8*2048*3 f32
  float* out_pts = (float*)d_out + (size_t)NB * NS * 3;   // 8*2048*128 f32
  int* qsel_ws = (int*)d_ws;                              // 16384*32 ints = 2 MiB

  fps_kernel<<<NB, 256, 0, stream>>>(xyz, new_xyz);
  ball_kernel<<<NB * NS, 256, 0, stream>>>(xyz, new_xyz, qsel_ws);
  mlp_kernel<<<NB * NS, 256, 0, stream>>>(xyz, points, new_xyz, qsel_ws,
                                          w0, b0, g0, bt0, m0, v0,
                                          w1, b1, g1, bt1, m1, v1,
                                          w2, b2, g2, bt2, m2, v2,
                                          out_pts);
}